// Round 2
// baseline (1536.887 us; speedup 1.0000x reference)
//
#include <hip/hip_runtime.h>
#include <math.h>

#define BMAX 4

__device__ __forceinline__ float sigmoidf_(float x) { return 1.f / (1.f + expf(-x)); }

// ---------------- fusion gate: s[n] = sigmoid(feat_mos[n] . fus_sp_w + b), per-batch counts
__global__ __launch_bounds__(256)
void k_fuse_s(const float* __restrict__ mos, const float* __restrict__ spw,
              const float* __restrict__ spb, const int* __restrict__ bids,
              float* __restrict__ s_out, float* __restrict__ cnt, int N)
{
    __shared__ float lcnt[BMAX];
    int tid = threadIdx.x;
    if (tid < BMAX) lcnt[tid] = 0.f;
    __syncthreads();
    int n = blockIdx.x * 256 + tid;
    if (n < N) {
        const float* mr = mos + (size_t)n * 64;
        float dot = 0.f;
        #pragma unroll
        for (int c = 0; c < 64; c += 4) {
            float4 m4 = *(const float4*)(mr + c);
            float4 w4 = *(const float4*)(spw + c);
            dot += m4.x * w4.x + m4.y * w4.y + m4.z * w4.z + m4.w * w4.w;
        }
        float s = sigmoidf_(dot + spb[0]);
        s_out[n] = s;
        atomicAdd(&lcnt[bids[n]], 1.f);
    }
    __syncthreads();
    if (tid < BMAX && lcnt[tid] != 0.f) atomicAdd(&cnt[tid], lcnt[tid]);
}

// ---------------- seg-sum of fm = s[n]*feat_sem[n,c] per (batch, channel)
__global__ __launch_bounds__(256)
void k_seg_fm(const float* __restrict__ fsem, const float* __restrict__ s_buf,
              const int* __restrict__ bids, float* __restrict__ seg, int N)
{
    __shared__ float lseg[BMAX * 64];
    int tid = threadIdx.x;
    lseg[tid] = 0.f;            // blockDim == 256 == BMAX*64
    __syncthreads();
    int c = tid & 63;
    int slot = blockIdx.x * 4 + (tid >> 6);
    int nslots = gridDim.x * 4;
    int chunk = (N + nslots - 1) / nslots;
    int n0 = slot * chunk;
    int n1 = min(N, n0 + chunk);
    float acc = 0.f; int curb = -1;
    for (int n = n0; n < n1; ++n) {
        int b = bids[n];
        if (b != curb) {
            if (curb >= 0) atomicAdd(&lseg[curb * 64 + c], acc);
            acc = 0.f; curb = b;
        }
        acc += s_buf[n] * fsem[(size_t)n * 64 + c];
    }
    if (curb >= 0) atomicAdd(&lseg[curb * 64 + c], acc);
    __syncthreads();
    atomicAdd(&seg[tid], lseg[tid]);
}

// ---------------- vec = softmax(seg_mean(fm) @ fus_ch_w + b) * 64   (one wave per batch)
__global__ void k_vec(const float* __restrict__ seg, const float* __restrict__ cnt,
                      const float* __restrict__ chw, const float* __restrict__ chb,
                      float* __restrict__ vec)
{
    int b = threadIdx.x >> 6;
    int c = threadIdx.x & 63;
    float mean = seg[b * 64 + c] / cnt[b];
    float v = chb[c];
    #pragma unroll 1
    for (int i = 0; i < 64; ++i) {
        float mi = __shfl(mean, i, 64);
        v += mi * chw[i * 64 + c];
    }
    float m = v;
    #pragma unroll
    for (int off = 32; off; off >>= 1) m = fmaxf(m, __shfl_xor(m, off, 64));
    float e = expf(v - m);
    float ssum = e;
    #pragma unroll
    for (int off = 32; off; off >>= 1) ssum += __shfl_xor(ssum, off, 64);
    vec[b * 64 + c] = e / ssum * 64.f;
}

// ---------------- gather-conv.  PRE: 0=none, 1=fusion-gate(conv0), 2=bn+relu, 3=att-scale
template<int CIN, int PRE, bool STATS, bool BIAS>
__global__ __launch_bounds__(256)
void k_conv(const float* __restrict__ in, const float* __restrict__ a1,
            const float* __restrict__ a2, const int* __restrict__ bids,
            const int* __restrict__ nbr, const float* __restrict__ W,
            const float* __restrict__ bias, float* __restrict__ out,
            float* __restrict__ bnsum, float* __restrict__ bnsq, int N)
{
    int tid = threadIdx.x;
    int n = blockIdx.x * 256 + tid;
    bool act = n < N;
    int nn = act ? n : (N - 1);
    float acc[32];
    #pragma unroll
    for (int o = 0; o < 32; ++o) acc[o] = 0.f;
    int b = bids[nn];
    const int* nr = nbr + (size_t)nn * 27;
    #pragma unroll 1
    for (int k = 0; k < 27; ++k) {
        int j = nr[k];
        float msk = (j >= 0) ? 1.f : 0.f;
        int jj = (j >= 0) ? j : 0;
        const float* inj = in + (size_t)jj * CIN;
        float sj = 0.f;
        if (PRE == 1) sj = a1[jj];
        const float* wk = W + k * CIN * 32;
        #pragma unroll
        for (int c4 = 0; c4 < CIN; c4 += 4) {
            float4 xv = *(const float4*)(inj + c4);
            float pre4[4];
            if (PRE == 1) {
                float4 vv = *(const float4*)(a2 + b * 64 + c4);
                pre4[0] = xv.x * (1.f + sj * vv.x);
                pre4[1] = xv.y * (1.f + sj * vv.y);
                pre4[2] = xv.z * (1.f + sj * vv.z);
                pre4[3] = xv.w * (1.f + sj * vv.w);
            } else if (PRE == 2) {
                pre4[0] = fmaxf(xv.x * a1[c4 + 0] + a2[c4 + 0], 0.f);
                pre4[1] = fmaxf(xv.y * a1[c4 + 1] + a2[c4 + 1], 0.f);
                pre4[2] = fmaxf(xv.z * a1[c4 + 2] + a2[c4 + 2], 0.f);
                pre4[3] = fmaxf(xv.w * a1[c4 + 3] + a2[c4 + 3], 0.f);
            } else if (PRE == 3) {
                float4 av = *(const float4*)(a1 + b * 32 + c4);
                pre4[0] = xv.x * av.x; pre4[1] = xv.y * av.y;
                pre4[2] = xv.z * av.z; pre4[3] = xv.w * av.w;
            } else {
                pre4[0] = xv.x; pre4[1] = xv.y; pre4[2] = xv.z; pre4[3] = xv.w;
            }
            #pragma unroll
            for (int cc = 0; cc < 4; ++cc) {
                float x = pre4[cc] * msk;
                const float* wr = wk + (c4 + cc) * 32;
                #pragma unroll
                for (int o = 0; o < 32; ++o) acc[o] += x * wr[o];
            }
        }
    }
    if (act) {
        float* orow = out + (size_t)nn * 32;
        #pragma unroll
        for (int o = 0; o < 32; o += 4) {
            float4 v;
            v.x = acc[o + 0] + (BIAS ? bias[o + 0] : 0.f);
            v.y = acc[o + 1] + (BIAS ? bias[o + 1] : 0.f);
            v.z = acc[o + 2] + (BIAS ? bias[o + 2] : 0.f);
            v.w = acc[o + 3] + (BIAS ? bias[o + 3] : 0.f);
            *(float4*)(orow + o) = v;
        }
    }
    if (STATS) {
        __shared__ float lsum[32];
        __shared__ float lsq[32];
        if (tid < 32) { lsum[tid] = 0.f; lsq[tid] = 0.f; }
        __syncthreads();
        #pragma unroll
        for (int i = 0; i < 32; ++i) {
            int c = (tid + i) & 31;
            float v = act ? acc[c] : 0.f;
            atomicAdd(&lsum[c], v);
            atomicAdd(&lsq[c], v * v);
        }
        __syncthreads();
        if (tid < 32) { atomicAdd(&bnsum[tid], lsum[tid]); atomicAdd(&bnsq[tid], lsq[tid]); }
    }
}

// ---------------- BN stats -> scale/shift
__global__ void k_stats(const float* __restrict__ sum, const float* __restrict__ sq,
                        const float* __restrict__ g, const float* __restrict__ bb,
                        float* __restrict__ sc, float* __restrict__ sh, float invN)
{
    int c = threadIdx.x;
    if (c < 32) {
        float m = sum[c] * invN;
        float v = sq[c] * invN - m * m;
        float s = g[c] * rsqrtf(v + 1e-4f);
        sc[c] = s;
        sh[c] = bb[c] - m * s;
    }
}

// ---------------- h1 = relu(bn2(t)+res); per-batch sum & max for attention
__global__ __launch_bounds__(256)
void k_comb1(const float* __restrict__ t, const float* __restrict__ res,
             const float* __restrict__ sc, const float* __restrict__ sh,
             const int* __restrict__ bids, float* __restrict__ hout,
             float* __restrict__ seg_sum, float* __restrict__ seg_max, int N)
{
    __shared__ float lsum[BMAX * 32];
    __shared__ int   lmax[BMAX * 32];
    int tid = threadIdx.x;
    if (tid < BMAX * 32) { lsum[tid] = 0.f; lmax[tid] = 0; }
    __syncthreads();
    int n = blockIdx.x * 256 + tid;
    if (n < N) {
        int b = bids[n];
        const float* tr = t + (size_t)n * 32;
        const float* rr = res + (size_t)n * 32;
        float vals[32];
        #pragma unroll
        for (int c = 0; c < 32; c += 4) {
            float4 tv = *(const float4*)(tr + c);
            float4 rv = *(const float4*)(rr + c);
            vals[c + 0] = fmaxf(tv.x * sc[c + 0] + sh[c + 0] + rv.x, 0.f);
            vals[c + 1] = fmaxf(tv.y * sc[c + 1] + sh[c + 1] + rv.y, 0.f);
            vals[c + 2] = fmaxf(tv.z * sc[c + 2] + sh[c + 2] + rv.z, 0.f);
            vals[c + 3] = fmaxf(tv.w * sc[c + 3] + sh[c + 3] + rv.w, 0.f);
            float4 ov; ov.x = vals[c+0]; ov.y = vals[c+1]; ov.z = vals[c+2]; ov.w = vals[c+3];
            *(float4*)(hout + (size_t)n * 32 + c) = ov;
        }
        #pragma unroll
        for (int i = 0; i < 32; ++i) {
            int c = (tid + i) & 31;
            atomicAdd(&lsum[b * 32 + c], vals[c]);
            atomicMax(&lmax[b * 32 + c], __float_as_int(vals[c]));
        }
    }
    __syncthreads();
    if (tid < BMAX * 32) {
        atomicAdd(&seg_sum[tid], lsum[tid]);
        atomicMax((int*)(seg_max + tid), lmax[tid]);
    }
}

// ---------------- channel attention (one wave per batch)
__global__ void k_att(const float* __restrict__ seg_sum, const float* __restrict__ seg_max,
                      const float* __restrict__ cnt, const float* __restrict__ ca1,
                      const float* __restrict__ ca2, float* __restrict__ att)
{
    int b = threadIdx.x >> 6;
    int lane = threadIdx.x & 63;
    bool actc = lane < 32;
    int c = lane & 31;
    float avg = actc ? seg_sum[b * 32 + c] / cnt[b] : 0.f;
    float mx  = actc ? seg_max[b * 32 + c] : 0.f;
    float h[8];
    #pragma unroll
    for (int i = 0; i < 4; ++i) {
        float w = actc ? ca1[c * 4 + i] : 0.f;
        h[i] = avg * w;
        h[i + 4] = mx * w;
    }
    #pragma unroll
    for (int off = 32; off; off >>= 1) {
        #pragma unroll
        for (int i = 0; i < 8; ++i) h[i] += __shfl_xor(h[i], off, 64);
    }
    if (actc) {
        float o = 0.f;
        #pragma unroll
        for (int i = 0; i < 4; ++i)
            o += (fmaxf(h[i], 0.f) + fmaxf(h[i + 4], 0.f)) * ca2[i * 32 + c];
        att[b * 32 + c] = sigmoidf_(o);
    }
}

// ---------------- h2 = relu(bn4(t) + h1*att); channel sums for final BN
__global__ __launch_bounds__(256)
void k_comb2(const float* __restrict__ t, const float* __restrict__ h1,
             const float* __restrict__ att, const float* __restrict__ sc,
             const float* __restrict__ sh, const int* __restrict__ bids,
             float* __restrict__ hout, float* __restrict__ bnsum,
             float* __restrict__ bnsq, int N)
{
    __shared__ float lsum[32];
    __shared__ float lsq[32];
    int tid = threadIdx.x;
    if (tid < 32) { lsum[tid] = 0.f; lsq[tid] = 0.f; }
    __syncthreads();
    int n = blockIdx.x * 256 + tid;
    bool act = n < N;
    float vals[32];
    if (act) {
        int b = bids[n];
        const float* tr = t + (size_t)n * 32;
        const float* hr = h1 + (size_t)n * 32;
        const float* ar = att + b * 32;
        #pragma unroll
        for (int c = 0; c < 32; c += 4) {
            float4 tv = *(const float4*)(tr + c);
            float4 hv = *(const float4*)(hr + c);
            float4 av = *(const float4*)(ar + c);
            vals[c + 0] = fmaxf(tv.x * sc[c + 0] + sh[c + 0] + hv.x * av.x, 0.f);
            vals[c + 1] = fmaxf(tv.y * sc[c + 1] + sh[c + 1] + hv.y * av.y, 0.f);
            vals[c + 2] = fmaxf(tv.z * sc[c + 2] + sh[c + 2] + hv.z * av.z, 0.f);
            vals[c + 3] = fmaxf(tv.w * sc[c + 3] + sh[c + 3] + hv.w * av.w, 0.f);
            float4 ov; ov.x = vals[c+0]; ov.y = vals[c+1]; ov.z = vals[c+2]; ov.w = vals[c+3];
            *(float4*)(hout + (size_t)n * 32 + c) = ov;
        }
    } else {
        #pragma unroll
        for (int c = 0; c < 32; ++c) vals[c] = 0.f;
    }
    #pragma unroll
    for (int i = 0; i < 32; ++i) {
        int c = (tid + i) & 31;
        atomicAdd(&lsum[c], vals[c]);
        atomicAdd(&lsq[c], vals[c] * vals[c]);
    }
    __syncthreads();
    if (tid < 32) { atomicAdd(&bnsum[tid], lsum[tid]); atomicAdd(&bnsq[tid], lsq[tid]); }
}

// ---------------- out = relu(bn5(h2)) @ lin_w + lin_b
__global__ __launch_bounds__(256)
void k_final(const float* __restrict__ h2, const float* __restrict__ sc,
             const float* __restrict__ sh, const float* __restrict__ lw,
             const float* __restrict__ lb, float* __restrict__ out, int N)
{
    int n = blockIdx.x * 256 + threadIdx.x;
    if (n >= N) return;
    const float* hr = h2 + (size_t)n * 32;
    float acc[26];
    #pragma unroll
    for (int o = 0; o < 26; ++o) acc[o] = lb[o];
    #pragma unroll
    for (int c4 = 0; c4 < 32; c4 += 4) {
        float4 hv = *(const float4*)(hr + c4);
        float xs[4] = { hv.x, hv.y, hv.z, hv.w };
        #pragma unroll
        for (int cc = 0; cc < 4; ++cc) {
            int c = c4 + cc;
            float x = fmaxf(xs[cc] * sc[c] + sh[c], 0.f);
            const float* wr = lw + c * 26;
            #pragma unroll
            for (int o = 0; o < 26; ++o) acc[o] += x * wr[o];
        }
    }
    float* orow = out + (size_t)n * 26;
    #pragma unroll
    for (int o = 0; o < 26; ++o) orow[o] = acc[o];
}

extern "C" void kernel_launch(void* const* d_in, const int* in_sizes, int n_in,
                              void* d_out, int out_size, void* d_ws, size_t ws_size,
                              hipStream_t stream)
{
    const float* feat_sem = (const float*)d_in[0];
    const float* feat_mos = (const float*)d_in[1];
    const float* fus_sp_w = (const float*)d_in[2];
    const float* fus_sp_b = (const float*)d_in[3];
    const float* fus_ch_w = (const float*)d_in[4];
    const float* fus_ch_b = (const float*)d_in[5];
    const float* conv_w   = (const float*)d_in[6];
    const float* conv_b   = (const float*)d_in[7];
    const float* r1c1_w   = (const float*)d_in[8];
    const float* r1g1     = (const float*)d_in[9];
    const float* r1b1     = (const float*)d_in[10];
    const float* r1c2_w   = (const float*)d_in[11];
    const float* r1g2     = (const float*)d_in[12];
    const float* r1b2     = (const float*)d_in[13];
    const float* ca1_w    = (const float*)d_in[14];
    const float* ca2_w    = (const float*)d_in[15];
    const float* r2c1_w   = (const float*)d_in[16];
    const float* r2g1     = (const float*)d_in[17];
    const float* r2b1     = (const float*)d_in[18];
    const float* r2c2_w   = (const float*)d_in[19];
    const float* r2g2     = (const float*)d_in[20];
    const float* r2b2     = (const float*)d_in[21];
    const float* out_g    = (const float*)d_in[22];
    const float* out_b    = (const float*)d_in[23];
    const float* lin_w    = (const float*)d_in[24];
    const float* lin_b    = (const float*)d_in[25];
    const int*   bids     = (const int*)d_in[26];
    const int*   nbr      = (const int*)d_in[27];
    int N = in_sizes[0] / 64;

    float* ws    = (float*)d_ws;
    float* s_buf = ws;
    float* h0    = ws + N;
    float* t1    = h0 + (size_t)N * 32;
    float* t2    = t1 + (size_t)N * 32;
    float* h1    = t2 + (size_t)N * 32;
    float* h2    = h1 + (size_t)N * 32;
    float* st    = h2 + (size_t)N * 32;
    float* seg_fm = st;            // 256
    float* cnt    = st + 256;      // 4
    float* vec    = st + 260;      // 256
    float* bnsum  = st + 516;      // 5*32
    float* bnsq   = st + 676;      // 5*32
    float* bnsc   = st + 836;      // 5*32
    float* bnsh   = st + 996;      // 5*32
    float* seg1s  = st + 1156;     // 128
    float* seg1m  = st + 1284;     // 128
    float* att    = st + 1412;     // 128  (total 1540 floats)

    hipMemsetAsync(st, 0, 1540 * sizeof(float), stream);

    int nb = (N + 255) / 256;
    float invN = 1.f / (float)N;

    k_fuse_s<<<nb, 256, 0, stream>>>(feat_mos, fus_sp_w, fus_sp_b, bids, s_buf, cnt, N);
    k_seg_fm<<<128, 256, 0, stream>>>(feat_sem, s_buf, bids, seg_fm, N);
    k_vec<<<1, 256, 0, stream>>>(seg_fm, cnt, fus_ch_w, fus_ch_b, vec);

    k_conv<64, 1, false, true><<<nb, 256, 0, stream>>>(feat_sem, s_buf, vec, bids, nbr,
        conv_w, conv_b, h0, nullptr, nullptr, N);

    k_conv<32, 0, true, false><<<nb, 256, 0, stream>>>(h0, nullptr, nullptr, bids, nbr,
        r1c1_w, nullptr, t1, bnsum + 0, bnsq + 0, N);
    k_stats<<<1, 32, 0, stream>>>(bnsum + 0, bnsq + 0, r1g1, r1b1, bnsc + 0, bnsh + 0, invN);

    k_conv<32, 2, true, false><<<nb, 256, 0, stream>>>(t1, bnsc + 0, bnsh + 0, bids, nbr,
        r1c2_w, nullptr, t2, bnsum + 32, bnsq + 32, N);
    k_stats<<<1, 32, 0, stream>>>(bnsum + 32, bnsq + 32, r1g2, r1b2, bnsc + 32, bnsh + 32, invN);

    k_comb1<<<nb, 256, 0, stream>>>(t2, h0, bnsc + 32, bnsh + 32, bids, h1, seg1s, seg1m, N);
    k_att<<<1, 256, 0, stream>>>(seg1s, seg1m, cnt, ca1_w, ca2_w, att);

    k_conv<32, 3, true, false><<<nb, 256, 0, stream>>>(h1, att, nullptr, bids, nbr,
        r2c1_w, nullptr, t1, bnsum + 64, bnsq + 64, N);
    k_stats<<<1, 32, 0, stream>>>(bnsum + 64, bnsq + 64, r2g1, r2b1, bnsc + 64, bnsh + 64, invN);

    k_conv<32, 2, true, false><<<nb, 256, 0, stream>>>(t1, bnsc + 64, bnsh + 64, bids, nbr,
        r2c2_w, nullptr, t2, bnsum + 96, bnsq + 96, N);
    k_stats<<<1, 32, 0, stream>>>(bnsum + 96, bnsq + 96, r2g2, r2b2, bnsc + 96, bnsh + 96, invN);

    k_comb2<<<nb, 256, 0, stream>>>(t2, h1, att, bnsc + 96, bnsh + 96, bids, h2,
        bnsum + 128, bnsq + 128, N);
    k_stats<<<1, 32, 0, stream>>>(bnsum + 128, bnsq + 128, out_g, out_b, bnsc + 128, bnsh + 128, invN);

    k_final<<<nb, 256, 0, stream>>>(h2, bnsc + 128, bnsh + 128, lin_w, lin_b, (float*)d_out, N);
}

// Round 3
// 657.096 us; speedup vs baseline: 2.3389x; 2.3389x over previous
//
#include <hip/hip_runtime.h>
#include <math.h>

#define BMAX 4
typedef __attribute__((ext_vector_type(8))) short s16x8;
typedef __attribute__((ext_vector_type(4))) float f32x4;

__device__ __forceinline__ float sigmoidf_(float x) { return 1.f / (1.f + expf(-x)); }

// f32 -> bf16 RNE
__device__ __forceinline__ ushort f2b(float f) {
    uint u = __float_as_uint(f);
    u = u + 0x7FFFu + ((u >> 16) & 1u);
    return (ushort)(u >> 16);
}
__device__ __forceinline__ uint pk2(float a, float b) {
    return (uint)f2b(a) | ((uint)f2b(b) << 16);
}

// ---------------- fusion gate: s[n] = sigmoid(feat_mos[n] . fus_sp_w + b), per-batch counts
__global__ __launch_bounds__(256)
void k_fuse_s(const float* __restrict__ mos, const float* __restrict__ spw,
              const float* __restrict__ spb, const int* __restrict__ bids,
              float* __restrict__ s_out, float* __restrict__ cnt, int N)
{
    __shared__ float lcnt[BMAX];
    int tid = threadIdx.x;
    if (tid < BMAX) lcnt[tid] = 0.f;
    __syncthreads();
    int n = blockIdx.x * 256 + tid;
    if (n < N) {
        const float* mr = mos + (size_t)n * 64;
        float dot = 0.f;
        #pragma unroll
        for (int c = 0; c < 64; c += 4) {
            float4 m4 = *(const float4*)(mr + c);
            float4 w4 = *(const float4*)(spw + c);
            dot += m4.x * w4.x + m4.y * w4.y + m4.z * w4.z + m4.w * w4.w;
        }
        float s = sigmoidf_(dot + spb[0]);
        s_out[n] = s;
        atomicAdd(&lcnt[bids[n]], 1.f);
    }
    __syncthreads();
    if (tid < BMAX && lcnt[tid] != 0.f) atomicAdd(&cnt[tid], lcnt[tid]);
}

// ---------------- seg-sum of fm = s[n]*feat_sem[n,c] per (batch, channel)
__global__ __launch_bounds__(256)
void k_seg_fm(const float* __restrict__ fsem, const float* __restrict__ s_buf,
              const int* __restrict__ bids, float* __restrict__ seg, int N)
{
    __shared__ float lseg[BMAX * 64];
    int tid = threadIdx.x;
    lseg[tid] = 0.f;
    __syncthreads();
    int c = tid & 63;
    int slot = blockIdx.x * 4 + (tid >> 6);
    int nslots = gridDim.x * 4;
    int chunk = (N + nslots - 1) / nslots;
    int n0 = slot * chunk;
    int n1 = min(N, n0 + chunk);
    float acc = 0.f; int curb = -1;
    for (int n = n0; n < n1; ++n) {
        int b = bids[n];
        if (b != curb) {
            if (curb >= 0) atomicAdd(&lseg[curb * 64 + c], acc);
            acc = 0.f; curb = b;
        }
        acc += s_buf[n] * fsem[(size_t)n * 64 + c];
    }
    if (curb >= 0) atomicAdd(&lseg[curb * 64 + c], acc);
    __syncthreads();
    atomicAdd(&seg[tid], lseg[tid]);
}

// ---------------- vec = softmax(seg_mean(fm) @ fus_ch_w + b) * 64
__global__ void k_vec(const float* __restrict__ seg, const float* __restrict__ cnt,
                      const float* __restrict__ chw, const float* __restrict__ chb,
                      float* __restrict__ vec)
{
    int b = threadIdx.x >> 6;
    int c = threadIdx.x & 63;
    float mean = seg[b * 64 + c] / cnt[b];
    float v = chb[c];
    #pragma unroll 1
    for (int i = 0; i < 64; ++i) {
        float mi = __shfl(mean, i, 64);
        v += mi * chw[i * 64 + c];
    }
    float m = v;
    #pragma unroll
    for (int off = 32; off; off >>= 1) m = fmaxf(m, __shfl_xor(m, off, 64));
    float e = expf(v - m);
    float ssum = e;
    #pragma unroll
    for (int off = 32; off; off >>= 1) ssum += __shfl_xor(ssum, off, 64);
    vec[b * 64 + c] = e / ssum * 64.f;
}

// ---------------- gated input -> bf16: g = feat_sem * (1 + s*vec[b])
__global__ __launch_bounds__(256)
void k_gate_cvt(const float* __restrict__ fs, const float* __restrict__ s_buf,
                const float* __restrict__ vec, const int* __restrict__ bids,
                ushort* __restrict__ out, int N)
{
    int n = blockIdx.x * 256 + threadIdx.x;
    if (n >= N) return;
    float s = s_buf[n];
    const float* vr = vec + bids[n] * 64;
    const float* fr = fs + (size_t)n * 64;
    ushort* orow = out + (size_t)n * 64;
    #pragma unroll
    for (int c = 0; c < 64; c += 8) {
        float4 f0 = *(const float4*)(fr + c);
        float4 f1 = *(const float4*)(fr + c + 4);
        float4 v0 = *(const float4*)(vr + c);
        float4 v1 = *(const float4*)(vr + c + 4);
        float g0 = f0.x * (1.f + s * v0.x), g1 = f0.y * (1.f + s * v0.y);
        float g2 = f0.z * (1.f + s * v0.z), g3 = f0.w * (1.f + s * v0.w);
        float g4 = f1.x * (1.f + s * v1.x), g5 = f1.y * (1.f + s * v1.y);
        float g6 = f1.z * (1.f + s * v1.z), g7 = f1.w * (1.f + s * v1.w);
        uint4 o; o.x = pk2(g0, g1); o.y = pk2(g2, g3); o.z = pk2(g4, g5); o.w = pk2(g6, g7);
        *(uint4*)(orow + c) = o;
    }
}

// ---------------- pack conv weights [27][CIN][32] f32 -> MFMA B-fragments bf16
// layout: [tap k][kc][ntile][lane][8], elem e = W[k][kc*32+(lane>>4)*8+e][nt*16+(lane&15)]
__global__ __launch_bounds__(256)
void k_wpack(const float* __restrict__ W, ushort* __restrict__ wpk, int CIN)
{
    int t = blockIdx.x * 256 + threadIdx.x;
    int nkc = CIN >> 5;
    int total = 27 * nkc * 128;
    if (t >= total) return;
    int lane = t & 63;
    int nt = (t >> 6) & 1;
    int kc = (t >> 7) % nkc;
    int k = t / (nkc * 128);
    int kk = kc * 32 + (lane >> 4) * 8;
    int col = nt * 16 + (lane & 15);
    const float* src = W + ((size_t)k * CIN + kk) * 32 + col;
    float v[8];
    #pragma unroll
    for (int e = 0; e < 8; ++e) v[e] = src[e * 32];
    uint4 o; o.x = pk2(v[0], v[1]); o.y = pk2(v[2], v[3]);
    o.z = pk2(v[4], v[5]); o.w = pk2(v[6], v[7]);
    *(uint4*)(wpk + (size_t)t * 8) = o;
}

// ---------------- MFMA gather-conv: wave = 32 voxels (2 M-tiles), 32 out-ch (2 N-tiles)
template<int CIN, bool STATS, bool BIAS, bool WB16>
__global__ __launch_bounds__(256)
void k_mconv(const ushort* __restrict__ inb, const int* __restrict__ nbr,
             const ushort* __restrict__ wpk, const float* __restrict__ bias,
             float* __restrict__ outf, ushort* __restrict__ outb,
             float* __restrict__ bnsum, float* __restrict__ bnsq, int N)
{
    __shared__ float lsum[32];
    __shared__ float lsq[32];
    int tid = threadIdx.x;
    if (STATS) {
        if (tid < 32) { lsum[tid] = 0.f; lsq[tid] = 0.f; }
        __syncthreads();
    }
    int lane = tid & 63;
    int gw = (blockIdx.x * 256 + tid) >> 6;
    int vbase = gw * 32;
    bool wact = vbase < N;
    float ps0 = 0.f, pq0 = 0.f, ps1 = 0.f, pq1 = 0.f;
    if (wact) {
        int row = lane & 15;
        int koff = (lane >> 4) * 8;     // bf16-elem offset within K-chunk
        f32x4 acc00 = {0.f,0.f,0.f,0.f}, acc01 = {0.f,0.f,0.f,0.f};
        f32x4 acc10 = {0.f,0.f,0.f,0.f}, acc11 = {0.f,0.f,0.f,0.f};
        const int* nb0 = nbr + (size_t)(vbase + row) * 27;
        const int* nb1 = nbr + (size_t)(vbase + 16 + row) * 27;
        #pragma unroll 3
        for (int k = 0; k < 27; ++k) {
            int j0 = nb0[k];
            int j1 = nb1[k];
            #pragma unroll
            for (int kc = 0; kc < CIN / 32; ++kc) {
                s16x8 a0 = {0,0,0,0,0,0,0,0};
                s16x8 a1 = {0,0,0,0,0,0,0,0};
                if (j0 >= 0) a0 = *(const s16x8*)(inb + (size_t)j0 * CIN + kc * 32 + koff);
                if (j1 >= 0) a1 = *(const s16x8*)(inb + (size_t)j1 * CIN + kc * 32 + koff);
                const ushort* wb = wpk + (size_t)(k * (CIN / 32) + kc) * 1024 + lane * 8;
                s16x8 b0 = *(const s16x8*)(wb);
                s16x8 b1 = *(const s16x8*)(wb + 512);
                acc00 = __builtin_amdgcn_mfma_f32_16x16x32_bf16(a0, b0, acc00, 0, 0, 0);
                acc01 = __builtin_amdgcn_mfma_f32_16x16x32_bf16(a0, b1, acc01, 0, 0, 0);
                acc10 = __builtin_amdgcn_mfma_f32_16x16x32_bf16(a1, b0, acc10, 0, 0, 0);
                acc11 = __builtin_amdgcn_mfma_f32_16x16x32_bf16(a1, b1, acc11, 0, 0, 0);
            }
        }
        // C layout: col = lane&15 (out-ch within tile), row = (lane>>4)*4 + i (voxel)
        int ccol = lane & 15;
        int crow = (lane >> 4) * 4;
        float b0v = BIAS ? bias[ccol] : 0.f;
        float b1v = BIAS ? bias[16 + ccol] : 0.f;
        #pragma unroll
        for (int mt = 0; mt < 2; ++mt) {
            const f32x4& A0 = mt ? acc10 : acc00;
            const f32x4& A1 = mt ? acc11 : acc01;
            #pragma unroll
            for (int i = 0; i < 4; ++i) {
                int v = vbase + mt * 16 + crow + i;
                float x0 = A0[i] + b0v;
                float x1 = A1[i] + b1v;
                outf[(size_t)v * 32 + ccol] = x0;
                outf[(size_t)v * 32 + 16 + ccol] = x1;
                if (WB16) {
                    outb[(size_t)v * 32 + ccol] = f2b(x0);
                    outb[(size_t)v * 32 + 16 + ccol] = f2b(x1);
                }
                if (STATS) { ps0 += x0; pq0 += x0 * x0; ps1 += x1; pq1 += x1 * x1; }
            }
        }
    }
    if (STATS) {
        ps0 += __shfl_xor(ps0, 16, 64); ps0 += __shfl_xor(ps0, 32, 64);
        pq0 += __shfl_xor(pq0, 16, 64); pq0 += __shfl_xor(pq0, 32, 64);
        ps1 += __shfl_xor(ps1, 16, 64); ps1 += __shfl_xor(ps1, 32, 64);
        pq1 += __shfl_xor(pq1, 16, 64); pq1 += __shfl_xor(pq1, 32, 64);
        if (lane < 16) {
            atomicAdd(&lsum[lane], ps0);
            atomicAdd(&lsq[lane], pq0);
            atomicAdd(&lsum[16 + lane], ps1);
            atomicAdd(&lsq[16 + lane], pq1);
        }
        __syncthreads();
        if (tid < 32) { atomicAdd(&bnsum[tid], lsum[tid]); atomicAdd(&bnsq[tid], lsq[tid]); }
    }
}

// ---------------- BN stats -> scale/shift
__global__ void k_stats(const float* __restrict__ sum, const float* __restrict__ sq,
                        const float* __restrict__ g, const float* __restrict__ bb,
                        float* __restrict__ sc, float* __restrict__ sh, float invN)
{
    int c = threadIdx.x;
    if (c < 32) {
        float m = sum[c] * invN;
        float v = sq[c] * invN - m * m;
        float s = g[c] * rsqrtf(v + 1e-4f);
        sc[c] = s;
        sh[c] = bb[c] - m * s;
    }
}

// ---------------- a_b = bf16(relu(t*sc+sh))
__global__ __launch_bounds__(256)
void k_bnact(const float* __restrict__ t, const float* __restrict__ sc,
             const float* __restrict__ sh, ushort* __restrict__ out, int N)
{
    int n = blockIdx.x * 256 + threadIdx.x;
    if (n >= N) return;
    const float* tr = t + (size_t)n * 32;
    ushort* orow = out + (size_t)n * 32;
    #pragma unroll
    for (int c = 0; c < 32; c += 8) {
        float4 t0 = *(const float4*)(tr + c);
        float4 t1 = *(const float4*)(tr + c + 4);
        float g0 = fmaxf(t0.x * sc[c+0] + sh[c+0], 0.f);
        float g1 = fmaxf(t0.y * sc[c+1] + sh[c+1], 0.f);
        float g2 = fmaxf(t0.z * sc[c+2] + sh[c+2], 0.f);
        float g3 = fmaxf(t0.w * sc[c+3] + sh[c+3], 0.f);
        float g4 = fmaxf(t1.x * sc[c+4] + sh[c+4], 0.f);
        float g5 = fmaxf(t1.y * sc[c+5] + sh[c+5], 0.f);
        float g6 = fmaxf(t1.z * sc[c+6] + sh[c+6], 0.f);
        float g7 = fmaxf(t1.w * sc[c+7] + sh[c+7], 0.f);
        uint4 o; o.x = pk2(g0, g1); o.y = pk2(g2, g3); o.z = pk2(g4, g5); o.w = pk2(g6, g7);
        *(uint4*)(orow + c) = o;
    }
}

// ---------------- h1 = relu(bn(t)+res); per-batch sum & max for attention
__global__ __launch_bounds__(256)
void k_comb1(const float* __restrict__ t, const float* __restrict__ res,
             const float* __restrict__ sc, const float* __restrict__ sh,
             const int* __restrict__ bids, float* __restrict__ hout,
             float* __restrict__ seg_sum, float* __restrict__ seg_max, int N)
{
    __shared__ float lsum[BMAX * 32];
    __shared__ int   lmax[BMAX * 32];
    int tid = threadIdx.x;
    if (tid < BMAX * 32) { lsum[tid] = 0.f; lmax[tid] = 0; }
    __syncthreads();
    int n = blockIdx.x * 256 + tid;
    if (n < N) {
        int b = bids[n];
        const float* tr = t + (size_t)n * 32;
        const float* rr = res + (size_t)n * 32;
        float vals[32];
        #pragma unroll
        for (int c = 0; c < 32; c += 4) {
            float4 tv = *(const float4*)(tr + c);
            float4 rv = *(const float4*)(rr + c);
            vals[c + 0] = fmaxf(tv.x * sc[c + 0] + sh[c + 0] + rv.x, 0.f);
            vals[c + 1] = fmaxf(tv.y * sc[c + 1] + sh[c + 1] + rv.y, 0.f);
            vals[c + 2] = fmaxf(tv.z * sc[c + 2] + sh[c + 2] + rv.z, 0.f);
            vals[c + 3] = fmaxf(tv.w * sc[c + 3] + sh[c + 3] + rv.w, 0.f);
            float4 ov; ov.x = vals[c+0]; ov.y = vals[c+1]; ov.z = vals[c+2]; ov.w = vals[c+3];
            *(float4*)(hout + (size_t)n * 32 + c) = ov;
        }
        #pragma unroll
        for (int i = 0; i < 32; ++i) {
            int c = (tid + i) & 31;
            atomicAdd(&lsum[b * 32 + c], vals[c]);
            atomicMax(&lmax[b * 32 + c], __float_as_int(vals[c]));
        }
    }
    __syncthreads();
    if (tid < BMAX * 32) {
        atomicAdd(&seg_sum[tid], lsum[tid]);
        atomicMax((int*)(seg_max + tid), lmax[tid]);
    }
}

// ---------------- channel attention
__global__ void k_att(const float* __restrict__ seg_sum, const float* __restrict__ seg_max,
                      const float* __restrict__ cnt, const float* __restrict__ ca1,
                      const float* __restrict__ ca2, float* __restrict__ att)
{
    int b = threadIdx.x >> 6;
    int lane = threadIdx.x & 63;
    bool actc = lane < 32;
    int c = lane & 31;
    float avg = actc ? seg_sum[b * 32 + c] / cnt[b] : 0.f;
    float mx  = actc ? seg_max[b * 32 + c] : 0.f;
    float h[8];
    #pragma unroll
    for (int i = 0; i < 4; ++i) {
        float w = actc ? ca1[c * 4 + i] : 0.f;
        h[i] = avg * w;
        h[i + 4] = mx * w;
    }
    #pragma unroll
    for (int off = 32; off; off >>= 1) {
        #pragma unroll
        for (int i = 0; i < 8; ++i) h[i] += __shfl_xor(h[i], off, 64);
    }
    if (actc) {
        float o = 0.f;
        #pragma unroll
        for (int i = 0; i < 4; ++i)
            o += (fmaxf(h[i], 0.f) + fmaxf(h[i + 4], 0.f)) * ca2[i * 32 + c];
        att[b * 32 + c] = sigmoidf_(o);
    }
}

// ---------------- hatt = h1*att[b] (f32 + bf16 mirror)
__global__ __launch_bounds__(256)
void k_scale_cvt(const float* __restrict__ h1, const float* __restrict__ att,
                 const int* __restrict__ bids, float* __restrict__ hatt,
                 ushort* __restrict__ hattb, int N)
{
    int n = blockIdx.x * 256 + threadIdx.x;
    if (n >= N) return;
    const float* hr = h1 + (size_t)n * 32;
    const float* ar = att + bids[n] * 32;
    float* of = hatt + (size_t)n * 32;
    ushort* ob = hattb + (size_t)n * 32;
    #pragma unroll
    for (int c = 0; c < 32; c += 8) {
        float4 h0 = *(const float4*)(hr + c);
        float4 h1v = *(const float4*)(hr + c + 4);
        float4 a0 = *(const float4*)(ar + c);
        float4 a1 = *(const float4*)(ar + c + 4);
        float g0 = h0.x * a0.x, g1 = h0.y * a0.y, g2 = h0.z * a0.z, g3 = h0.w * a0.w;
        float g4 = h1v.x * a1.x, g5 = h1v.y * a1.y, g6 = h1v.z * a1.z, g7 = h1v.w * a1.w;
        float4 w0; w0.x = g0; w0.y = g1; w0.z = g2; w0.w = g3;
        float4 w1; w1.x = g4; w1.y = g5; w1.z = g6; w1.w = g7;
        *(float4*)(of + c) = w0;
        *(float4*)(of + c + 4) = w1;
        uint4 o; o.x = pk2(g0, g1); o.y = pk2(g2, g3); o.z = pk2(g4, g5); o.w = pk2(g6, g7);
        *(uint4*)(ob + c) = o;
    }
}

// ---------------- h2 = relu(bn(t) + hatt); channel sums for final BN
__global__ __launch_bounds__(256)
void k_comb2(const float* __restrict__ t, const float* __restrict__ hres,
             const float* __restrict__ sc, const float* __restrict__ sh,
             float* __restrict__ hout, float* __restrict__ bnsum,
             float* __restrict__ bnsq, int N)
{
    __shared__ float lsum[32];
    __shared__ float lsq[32];
    int tid = threadIdx.x;
    if (tid < 32) { lsum[tid] = 0.f; lsq[tid] = 0.f; }
    __syncthreads();
    int n = blockIdx.x * 256 + tid;
    bool act = n < N;
    float vals[32];
    if (act) {
        const float* tr = t + (size_t)n * 32;
        const float* hr = hres + (size_t)n * 32;
        #pragma unroll
        for (int c = 0; c < 32; c += 4) {
            float4 tv = *(const float4*)(tr + c);
            float4 hv = *(const float4*)(hr + c);
            vals[c + 0] = fmaxf(tv.x * sc[c + 0] + sh[c + 0] + hv.x, 0.f);
            vals[c + 1] = fmaxf(tv.y * sc[c + 1] + sh[c + 1] + hv.y, 0.f);
            vals[c + 2] = fmaxf(tv.z * sc[c + 2] + sh[c + 2] + hv.z, 0.f);
            vals[c + 3] = fmaxf(tv.w * sc[c + 3] + sh[c + 3] + hv.w, 0.f);
            float4 ov; ov.x = vals[c+0]; ov.y = vals[c+1]; ov.z = vals[c+2]; ov.w = vals[c+3];
            *(float4*)(hout + (size_t)n * 32 + c) = ov;
        }
    } else {
        #pragma unroll
        for (int c = 0; c < 32; ++c) vals[c] = 0.f;
    }
    #pragma unroll
    for (int i = 0; i < 32; ++i) {
        int c = (tid + i) & 31;
        atomicAdd(&lsum[c], vals[c]);
        atomicAdd(&lsq[c], vals[c] * vals[c]);
    }
    __syncthreads();
    if (tid < 32) { atomicAdd(&bnsum[tid], lsum[tid]); atomicAdd(&bnsq[tid], lsq[tid]); }
}

// ---------------- out = relu(bn5(h2)) @ lin_w + lin_b
__global__ __launch_bounds__(256)
void k_final(const float* __restrict__ h2, const float* __restrict__ sc,
             const float* __restrict__ sh, const float* __restrict__ lw,
             const float* __restrict__ lb, float* __restrict__ out, int N)
{
    int n = blockIdx.x * 256 + threadIdx.x;
    if (n >= N) return;
    const float* hr = h2 + (size_t)n * 32;
    float acc[26];
    #pragma unroll
    for (int o = 0; o < 26; ++o) acc[o] = lb[o];
    #pragma unroll
    for (int c4 = 0; c4 < 32; c4 += 4) {
        float4 hv = *(const float4*)(hr + c4);
        float xs[4] = { hv.x, hv.y, hv.z, hv.w };
        #pragma unroll
        for (int cc = 0; cc < 4; ++cc) {
            int c = c4 + cc;
            float x = fmaxf(xs[cc] * sc[c] + sh[c], 0.f);
            const float* wr = lw + c * 26;
            #pragma unroll
            for (int o = 0; o < 26; ++o) acc[o] += x * wr[o];
        }
    }
    float* orow = out + (size_t)n * 26;
    #pragma unroll
    for (int o = 0; o < 26; ++o) orow[o] = acc[o];
}

extern "C" void kernel_launch(void* const* d_in, const int* in_sizes, int n_in,
                              void* d_out, int out_size, void* d_ws, size_t ws_size,
                              hipStream_t stream)
{
    const float* feat_sem = (const float*)d_in[0];
    const float* feat_mos = (const float*)d_in[1];
    const float* fus_sp_w = (const float*)d_in[2];
    const float* fus_sp_b = (const float*)d_in[3];
    const float* fus_ch_w = (const float*)d_in[4];
    const float* fus_ch_b = (const float*)d_in[5];
    const float* conv_w   = (const float*)d_in[6];
    const float* conv_b   = (const float*)d_in[7];
    const float* r1c1_w   = (const float*)d_in[8];
    const float* r1g1     = (const float*)d_in[9];
    const float* r1b1     = (const float*)d_in[10];
    const float* r1c2_w   = (const float*)d_in[11];
    const float* r1g2     = (const float*)d_in[12];
    const float* r1b2     = (const float*)d_in[13];
    const float* ca1_w    = (const float*)d_in[14];
    const float* ca2_w    = (const float*)d_in[15];
    const float* r2c1_w   = (const float*)d_in[16];
    const float* r2g1     = (const float*)d_in[17];
    const float* r2b1     = (const float*)d_in[18];
    const float* r2c2_w   = (const float*)d_in[19];
    const float* r2g2     = (const float*)d_in[20];
    const float* r2b2     = (const float*)d_in[21];
    const float* out_g    = (const float*)d_in[22];
    const float* out_b    = (const float*)d_in[23];
    const float* lin_w    = (const float*)d_in[24];
    const float* lin_b    = (const float*)d_in[25];
    const int*   bids     = (const int*)d_in[26];
    const int*   nbr      = (const int*)d_in[27];
    int N = in_sizes[0] / 64;

    float* ws = (float*)d_ws;
    float* S1 = ws;                              // N*32 f32
    float* S2 = ws + (size_t)32 * N;
    float* S3 = ws + (size_t)64 * N;
    float* S4 = ws + (size_t)96 * N;
    ushort* BB1 = (ushort*)(ws + (size_t)128 * N);   // N*32 bf16
    ushort* BB2 = (ushort*)(ws + (size_t)144 * N);   // N*32 bf16
    float* sbuf = (float*)BB2;                       // s gate (dead before BB2 written)
    ushort* FGB = (ushort*)S3;                       // gated input bf16 N*64 (dead before S3 written)
    float* st = ws + (size_t)160 * N;
    float* seg_fm = st;            // 256
    float* cnt    = st + 256;      // 4
    float* vec    = st + 260;      // 256
    float* bnsum  = st + 516;      // 5*32
    float* bnsq   = st + 676;      // 5*32
    float* bnsc   = st + 836;      // 5*32
    float* bnsh   = st + 996;      // 5*32
    float* seg1s  = st + 1156;     // 128
    float* seg1m  = st + 1284;     // 128
    float* att    = st + 1412;     // 128 (stats end 1540)
    ushort* wpk0 = (ushort*)(st + 1600);   // 27*2*2*64*8 = 55296 ushorts
    ushort* wpk1 = wpk0 + 55296;           // 27648 each
    ushort* wpk2 = wpk1 + 27648;
    ushort* wpk3 = wpk2 + 27648;
    ushort* wpk4 = wpk3 + 27648;

    hipMemsetAsync(st, 0, 1540 * sizeof(float), stream);

    int nb = (N + 255) / 256;
    int nw = (N + 127) / 128;   // mconv: 128 voxels/block
    float invN = 1.f / (float)N;

    k_wpack<<<27, 256, 0, stream>>>(conv_w, wpk0, 64);
    k_wpack<<<14, 256, 0, stream>>>(r1c1_w, wpk1, 32);
    k_wpack<<<14, 256, 0, stream>>>(r1c2_w, wpk2, 32);
    k_wpack<<<14, 256, 0, stream>>>(r2c1_w, wpk3, 32);
    k_wpack<<<14, 256, 0, stream>>>(r2c2_w, wpk4, 32);

    k_fuse_s<<<nb, 256, 0, stream>>>(feat_mos, fus_sp_w, fus_sp_b, bids, sbuf, cnt, N);
    k_seg_fm<<<128, 256, 0, stream>>>(feat_sem, sbuf, bids, seg_fm, N);
    k_vec<<<1, 256, 0, stream>>>(seg_fm, cnt, fus_ch_w, fus_ch_b, vec);
    k_gate_cvt<<<nb, 256, 0, stream>>>(feat_sem, sbuf, vec, bids, FGB, N);

    k_mconv<64, false, true, true><<<nw, 256, 0, stream>>>(FGB, nbr, wpk0, conv_b,
        S1, BB1, nullptr, nullptr, N);

    k_mconv<32, true, false, false><<<nw, 256, 0, stream>>>(BB1, nbr, wpk1, nullptr,
        S2, nullptr, bnsum + 0, bnsq + 0, N);
    k_stats<<<1, 32, 0, stream>>>(bnsum + 0, bnsq + 0, r1g1, r1b1, bnsc + 0, bnsh + 0, invN);
    k_bnact<<<nb, 256, 0, stream>>>(S2, bnsc + 0, bnsh + 0, BB2, N);

    k_mconv<32, true, false, false><<<nw, 256, 0, stream>>>(BB2, nbr, wpk2, nullptr,
        S3, nullptr, bnsum + 32, bnsq + 32, N);
    k_stats<<<1, 32, 0, stream>>>(bnsum + 32, bnsq + 32, r1g2, r1b2, bnsc + 32, bnsh + 32, invN);

    k_comb1<<<nb, 256, 0, stream>>>(S3, S1, bnsc + 32, bnsh + 32, bids, S4, seg1s, seg1m, N);
    k_att<<<1, 256, 0, stream>>>(seg1s, seg1m, cnt, ca1_w, ca2_w, att);
    k_scale_cvt<<<nb, 256, 0, stream>>>(S4, att, bids, S2, BB1, N);

    k_mconv<32, true, false, false><<<nw, 256, 0, stream>>>(BB1, nbr, wpk3, nullptr,
        S1, nullptr, bnsum + 64, bnsq + 64, N);
    k_stats<<<1, 32, 0, stream>>>(bnsum + 64, bnsq + 64, r2g1, r2b1, bnsc + 64, bnsh + 64, invN);
    k_bnact<<<nb, 256, 0, stream>>>(S1, bnsc + 64, bnsh + 64, BB2, N);

    k_mconv<32, true, false, false><<<nw, 256, 0, stream>>>(BB2, nbr, wpk4, nullptr,
        S3, nullptr, bnsum + 96, bnsq + 96, N);
    k_stats<<<1, 32, 0, stream>>>(bnsum + 96, bnsq + 96, r2g2, r2b2, bnsc + 96, bnsh + 96, invN);

    k_comb2<<<nb, 256, 0, stream>>>(S3, S2, bnsc + 96, bnsh + 96, S4,
        bnsum + 128, bnsq + 128, N);
    k_stats<<<1, 32, 0, stream>>>(bnsum + 128, bnsq + 128, out_g, out_b, bnsc + 128, bnsh + 128, invN);

    k_final<<<nb, 256, 0, stream>>>(S4, bnsc + 128, bnsh + 128, lin_w, lin_b, (float*)d_out, N);
}

// Round 4
// 567.748 us; speedup vs baseline: 2.7070x; 1.1574x over previous
//
#include <hip/hip_runtime.h>
#include <math.h>

#define BMAX 4
typedef __attribute__((ext_vector_type(8))) short s16x8;
typedef __attribute__((ext_vector_type(4))) float f32x4;

__device__ __forceinline__ float sigmoidf_(float x) { return 1.f / (1.f + expf(-x)); }

// f32 -> bf16 RNE
__device__ __forceinline__ ushort f2b(float f) {
    uint u = __float_as_uint(f);
    u = u + 0x7FFFu + ((u >> 16) & 1u);
    return (ushort)(u >> 16);
}
__device__ __forceinline__ uint pk2(float a, float b) {
    return (uint)f2b(a) | ((uint)f2b(b) << 16);
}

// ---------------- fusion gate: s[n] = sigmoid(feat_mos[n] . fus_sp_w + b), per-batch counts
__global__ __launch_bounds__(256)
void k_fuse_s(const float* __restrict__ mos, const float* __restrict__ spw,
              const float* __restrict__ spb, const int* __restrict__ bids,
              float* __restrict__ s_out, float* __restrict__ cnt, int N)
{
    __shared__ float lcnt[BMAX];
    int tid = threadIdx.x;
    if (tid < BMAX) lcnt[tid] = 0.f;
    __syncthreads();
    int n = blockIdx.x * 256 + tid;
    if (n < N) {
        const float* mr = mos + (size_t)n * 64;
        float dot = 0.f;
        #pragma unroll
        for (int c = 0; c < 64; c += 4) {
            float4 m4 = *(const float4*)(mr + c);
            float4 w4 = *(const float4*)(spw + c);
            dot += m4.x * w4.x + m4.y * w4.y + m4.z * w4.z + m4.w * w4.w;
        }
        float s = sigmoidf_(dot + spb[0]);
        s_out[n] = s;
        atomicAdd(&lcnt[bids[n]], 1.f);
    }
    __syncthreads();
    if (tid < BMAX && lcnt[tid] != 0.f) atomicAdd(&cnt[tid], lcnt[tid]);
}

// ---------------- stage 1: per-block partial seg-sums of fm = s[n]*feat_sem[n,c]
__global__ __launch_bounds__(256)
void k_seg_part(const float* __restrict__ fsem, const float* __restrict__ s_buf,
                const int* __restrict__ bids, float* __restrict__ part, int N)
{
    __shared__ float lseg[BMAX * 64];
    int tid = threadIdx.x;
    lseg[tid] = 0.f;
    __syncthreads();
    int c = tid & 63;
    int slot = blockIdx.x * 4 + (tid >> 6);
    int nslots = gridDim.x * 4;
    int chunk = (N + nslots - 1) / nslots;
    int n0 = slot * chunk;
    int n1 = min(N, n0 + chunk);
    float acc = 0.f; int curb = -1;
    int n = n0;
    for (; n + 4 <= n1; n += 4) {
        int b0 = bids[n], b3 = bids[n + 3];
        float s0 = s_buf[n], s1 = s_buf[n + 1], s2 = s_buf[n + 2], s3 = s_buf[n + 3];
        float f0 = fsem[(size_t)n * 64 + c];
        float f1 = fsem[(size_t)(n + 1) * 64 + c];
        float f2 = fsem[(size_t)(n + 2) * 64 + c];
        float f3 = fsem[(size_t)(n + 3) * 64 + c];
        if (b0 == b3) {
            if (b0 != curb) {
                if (curb >= 0) atomicAdd(&lseg[curb * 64 + c], acc);
                acc = 0.f; curb = b0;
            }
            acc += s0 * f0 + s1 * f1 + s2 * f2 + s3 * f3;
        } else {
            int bb[4] = { b0, bids[n + 1], bids[n + 2], b3 };
            float sv[4] = { s0, s1, s2, s3 };
            float fv[4] = { f0, f1, f2, f3 };
            #pragma unroll
            for (int q = 0; q < 4; ++q) {
                if (bb[q] != curb) {
                    if (curb >= 0) atomicAdd(&lseg[curb * 64 + c], acc);
                    acc = 0.f; curb = bb[q];
                }
                acc += sv[q] * fv[q];
            }
        }
    }
    for (; n < n1; ++n) {
        int b = bids[n];
        if (b != curb) {
            if (curb >= 0) atomicAdd(&lseg[curb * 64 + c], acc);
            acc = 0.f; curb = b;
        }
        acc += s_buf[n] * fsem[(size_t)n * 64 + c];
    }
    if (curb >= 0) atomicAdd(&lseg[curb * 64 + c], acc);
    __syncthreads();
    part[(size_t)blockIdx.x * 256 + tid] = lseg[tid];
}

// ---------------- stage 2: reduce partials -> seg[256]
__global__ void k_seg_red(const float* __restrict__ part, float* __restrict__ seg, int nblk)
{
    int tid = threadIdx.x;
    float a = 0.f;
    #pragma unroll 8
    for (int i = 0; i < nblk; ++i) a += part[(size_t)i * 256 + tid];
    seg[tid] = a;
}

// ---------------- vec = softmax(seg_mean(fm) @ fus_ch_w + b) * 64
__global__ void k_vec(const float* __restrict__ seg, const float* __restrict__ cnt,
                      const float* __restrict__ chw, const float* __restrict__ chb,
                      float* __restrict__ vec)
{
    int b = threadIdx.x >> 6;
    int c = threadIdx.x & 63;
    float mean = seg[b * 64 + c] / cnt[b];
    float v = chb[c];
    #pragma unroll 1
    for (int i = 0; i < 64; ++i) {
        float mi = __shfl(mean, i, 64);
        v += mi * chw[i * 64 + c];
    }
    float m = v;
    #pragma unroll
    for (int off = 32; off; off >>= 1) m = fmaxf(m, __shfl_xor(m, off, 64));
    float e = expf(v - m);
    float ssum = e;
    #pragma unroll
    for (int off = 32; off; off >>= 1) ssum += __shfl_xor(ssum, off, 64);
    vec[b * 64 + c] = e / ssum * 64.f;
}

// ---------------- gated input -> bf16: g = feat_sem * (1 + s*vec[b])
__global__ __launch_bounds__(256)
void k_gate_cvt(const float* __restrict__ fs, const float* __restrict__ s_buf,
                const float* __restrict__ vec, const int* __restrict__ bids,
                ushort* __restrict__ out, int N)
{
    int n = blockIdx.x * 256 + threadIdx.x;
    if (n >= N) return;
    float s = s_buf[n];
    const float* vr = vec + bids[n] * 64;
    const float* fr = fs + (size_t)n * 64;
    ushort* orow = out + (size_t)n * 64;
    #pragma unroll
    for (int c = 0; c < 64; c += 8) {
        float4 f0 = *(const float4*)(fr + c);
        float4 f1 = *(const float4*)(fr + c + 4);
        float4 v0 = *(const float4*)(vr + c);
        float4 v1 = *(const float4*)(vr + c + 4);
        float g0 = f0.x * (1.f + s * v0.x), g1 = f0.y * (1.f + s * v0.y);
        float g2 = f0.z * (1.f + s * v0.z), g3 = f0.w * (1.f + s * v0.w);
        float g4 = f1.x * (1.f + s * v1.x), g5 = f1.y * (1.f + s * v1.y);
        float g6 = f1.z * (1.f + s * v1.z), g7 = f1.w * (1.f + s * v1.w);
        uint4 o; o.x = pk2(g0, g1); o.y = pk2(g2, g3); o.z = pk2(g4, g5); o.w = pk2(g6, g7);
        *(uint4*)(orow + c) = o;
    }
}

// ---------------- pack one weight element into MFMA B-fragment layout
__device__ __forceinline__ void wpack_one(const float* __restrict__ W, int CIN,
                                          int tt, ushort* __restrict__ dst)
{
    int nkc = CIN >> 5;
    int lane = tt & 63;
    int nt = (tt >> 6) & 1;
    int kc = (tt >> 7) % nkc;
    int k = tt / (nkc * 128);
    int kk = kc * 32 + (lane >> 4) * 8;
    int col = nt * 16 + (lane & 15);
    const float* src = W + ((size_t)k * CIN + kk) * 32 + col;
    float v[8];
    #pragma unroll
    for (int e = 0; e < 8; ++e) v[e] = src[e * 32];
    uint4 o; o.x = pk2(v[0], v[1]); o.y = pk2(v[2], v[3]);
    o.z = pk2(v[4], v[5]); o.w = pk2(v[6], v[7]);
    *(uint4*)(dst + (size_t)tt * 8) = o;
}

// ---------------- pack all 5 conv weight tensors in one launch
// P layout: [wpk0: 55296][wpk1..4: 27648 each] ushorts
__global__ __launch_bounds__(256)
void k_wpack_all(const float* __restrict__ W0, const float* __restrict__ W1,
                 const float* __restrict__ W2, const float* __restrict__ W3,
                 const float* __restrict__ W4, ushort* __restrict__ P)
{
    int t = blockIdx.x * 256 + threadIdx.x;
    if (t < 6912) {
        wpack_one(W0, 64, t, P);
    } else {
        int r = t - 6912;
        int s = r / 3456;
        int tt = r % 3456;
        if (s >= 4) return;
        const float* W = (s == 0) ? W1 : (s == 1) ? W2 : (s == 2) ? W3 : W4;
        wpack_one(W, 32, tt, P + 55296 + s * 27648);
    }
}

// ---------------- MFMA gather-conv: wave = 32 voxels (2 M-tiles), 32 out-ch (2 N-tiles)
template<int CIN, bool STATS, bool BIAS, bool WB16>
__global__ __launch_bounds__(256)
void k_mconv(const ushort* __restrict__ inb, const int* __restrict__ nbr,
             const ushort* __restrict__ wpk, const float* __restrict__ bias,
             float* __restrict__ outf, ushort* __restrict__ outb,
             float* __restrict__ bnsum, float* __restrict__ bnsq, int N)
{
    __shared__ float lsum[32];
    __shared__ float lsq[32];
    int tid = threadIdx.x;
    if (STATS) {
        if (tid < 32) { lsum[tid] = 0.f; lsq[tid] = 0.f; }
        __syncthreads();
    }
    int lane = tid & 63;
    int gw = (blockIdx.x * 256 + tid) >> 6;
    int vbase = gw * 32;
    bool wact = vbase < N;
    float ps0 = 0.f, pq0 = 0.f, ps1 = 0.f, pq1 = 0.f;
    if (wact) {
        int row = lane & 15;
        int koff = (lane >> 4) * 8;     // bf16-elem offset within K-chunk
        f32x4 acc00 = {0.f,0.f,0.f,0.f}, acc01 = {0.f,0.f,0.f,0.f};
        f32x4 acc10 = {0.f,0.f,0.f,0.f}, acc11 = {0.f,0.f,0.f,0.f};
        const int* nb0 = nbr + (size_t)(vbase + row) * 27;
        const int* nb1 = nbr + (size_t)(vbase + 16 + row) * 27;
        #pragma unroll
        for (int k = 0; k < 27; ++k) {
            int j0 = nb0[k];
            int j1 = nb1[k];
            #pragma unroll
            for (int kc = 0; kc < CIN / 32; ++kc) {
                s16x8 a0 = {0,0,0,0,0,0,0,0};
                s16x8 a1 = {0,0,0,0,0,0,0,0};
                if (j0 >= 0) a0 = *(const s16x8*)(inb + (size_t)j0 * CIN + kc * 32 + koff);
                if (j1 >= 0) a1 = *(const s16x8*)(inb + (size_t)j1 * CIN + kc * 32 + koff);
                const ushort* wb = wpk + (size_t)(k * (CIN / 32) + kc) * 1024 + lane * 8;
                s16x8 b0 = *(const s16x8*)(wb);
                s16x8 b1 = *(const s16x8*)(wb + 512);
                acc00 = __builtin_amdgcn_mfma_f32_16x16x32_bf16(a0, b0, acc00, 0, 0, 0);
                acc01 = __builtin_amdgcn_mfma_f32_16x16x32_bf16(a0, b1, acc01, 0, 0, 0);
                acc10 = __builtin_amdgcn_mfma_f32_16x16x32_bf16(a1, b0, acc10, 0, 0, 0);
                acc11 = __builtin_amdgcn_mfma_f32_16x16x32_bf16(a1, b1, acc11, 0, 0, 0);
            }
        }
        // C layout: col = lane&15 (out-ch within tile), row = (lane>>4)*4 + i (voxel)
        int ccol = lane & 15;
        int crow = (lane >> 4) * 4;
        float b0v = BIAS ? bias[ccol] : 0.f;
        float b1v = BIAS ? bias[16 + ccol] : 0.f;
        #pragma unroll
        for (int mt = 0; mt < 2; ++mt) {
            const f32x4& A0 = mt ? acc10 : acc00;
            const f32x4& A1 = mt ? acc11 : acc01;
            #pragma unroll
            for (int i = 0; i < 4; ++i) {
                int v = vbase + mt * 16 + crow + i;
                float x0 = A0[i] + b0v;
                float x1 = A1[i] + b1v;
                outf[(size_t)v * 32 + ccol] = x0;
                outf[(size_t)v * 32 + 16 + ccol] = x1;
                if (WB16) {
                    outb[(size_t)v * 32 + ccol] = f2b(x0);
                    outb[(size_t)v * 32 + 16 + ccol] = f2b(x1);
                }
                if (STATS) { ps0 += x0; pq0 += x0 * x0; ps1 += x1; pq1 += x1 * x1; }
            }
        }
    }
    if (STATS) {
        ps0 += __shfl_xor(ps0, 16, 64); ps0 += __shfl_xor(ps0, 32, 64);
        pq0 += __shfl_xor(pq0, 16, 64); pq0 += __shfl_xor(pq0, 32, 64);
        ps1 += __shfl_xor(ps1, 16, 64); ps1 += __shfl_xor(ps1, 32, 64);
        pq1 += __shfl_xor(pq1, 16, 64); pq1 += __shfl_xor(pq1, 32, 64);
        if (lane < 16) {
            atomicAdd(&lsum[lane], ps0);
            atomicAdd(&lsq[lane], pq0);
            atomicAdd(&lsum[16 + lane], ps1);
            atomicAdd(&lsq[16 + lane], pq1);
        }
        __syncthreads();
        if (tid < 32) { atomicAdd(&bnsum[tid], lsum[tid]); atomicAdd(&bnsq[tid], lsq[tid]); }
    }
}

// ---------------- BN stats -> scale/shift
__global__ void k_stats(const float* __restrict__ sum, const float* __restrict__ sq,
                        const float* __restrict__ g, const float* __restrict__ bb,
                        float* __restrict__ sc, float* __restrict__ sh, float invN)
{
    int c = threadIdx.x;
    if (c < 32) {
        float m = sum[c] * invN;
        float v = sq[c] * invN - m * m;
        float s = g[c] * rsqrtf(v + 1e-4f);
        sc[c] = s;
        sh[c] = bb[c] - m * s;
    }
}

// ---------------- a_b = bf16(relu(t*sc+sh))
__global__ __launch_bounds__(256)
void k_bnact(const float* __restrict__ t, const float* __restrict__ sc,
             const float* __restrict__ sh, ushort* __restrict__ out, int N)
{
    int n = blockIdx.x * 256 + threadIdx.x;
    if (n >= N) return;
    const float* tr = t + (size_t)n * 32;
    ushort* orow = out + (size_t)n * 32;
    #pragma unroll
    for (int c = 0; c < 32; c += 8) {
        float4 t0 = *(const float4*)(tr + c);
        float4 t1 = *(const float4*)(tr + c + 4);
        float g0 = fmaxf(t0.x * sc[c+0] + sh[c+0], 0.f);
        float g1 = fmaxf(t0.y * sc[c+1] + sh[c+1], 0.f);
        float g2 = fmaxf(t0.z * sc[c+2] + sh[c+2], 0.f);
        float g3 = fmaxf(t0.w * sc[c+3] + sh[c+3], 0.f);
        float g4 = fmaxf(t1.x * sc[c+4] + sh[c+4], 0.f);
        float g5 = fmaxf(t1.y * sc[c+5] + sh[c+5], 0.f);
        float g6 = fmaxf(t1.z * sc[c+6] + sh[c+6], 0.f);
        float g7 = fmaxf(t1.w * sc[c+7] + sh[c+7], 0.f);
        uint4 o; o.x = pk2(g0, g1); o.y = pk2(g2, g3); o.z = pk2(g4, g5); o.w = pk2(g6, g7);
        *(uint4*)(orow + c) = o;
    }
}

// ---------------- h1 = relu(bn(t)+res); per-batch sum & max for attention
__global__ __launch_bounds__(256)
void k_comb1(const float* __restrict__ t, const float* __restrict__ res,
             const float* __restrict__ sc, const float* __restrict__ sh,
             const int* __restrict__ bids, float* __restrict__ hout,
             float* __restrict__ seg_sum, float* __restrict__ seg_max, int N)
{
    __shared__ float lsum[BMAX * 32];
    __shared__ int   lmax[BMAX * 32];
    int tid = threadIdx.x;
    if (tid < BMAX * 32) { lsum[tid] = 0.f; lmax[tid] = 0; }
    __syncthreads();
    int n = blockIdx.x * 256 + tid;
    if (n < N) {
        int b = bids[n];
        const float* tr = t + (size_t)n * 32;
        const float* rr = res + (size_t)n * 32;
        float vals[32];
        #pragma unroll
        for (int c = 0; c < 32; c += 4) {
            float4 tv = *(const float4*)(tr + c);
            float4 rv = *(const float4*)(rr + c);
            vals[c + 0] = fmaxf(tv.x * sc[c + 0] + sh[c + 0] + rv.x, 0.f);
            vals[c + 1] = fmaxf(tv.y * sc[c + 1] + sh[c + 1] + rv.y, 0.f);
            vals[c + 2] = fmaxf(tv.z * sc[c + 2] + sh[c + 2] + rv.z, 0.f);
            vals[c + 3] = fmaxf(tv.w * sc[c + 3] + sh[c + 3] + rv.w, 0.f);
            float4 ov; ov.x = vals[c+0]; ov.y = vals[c+1]; ov.z = vals[c+2]; ov.w = vals[c+3];
            *(float4*)(hout + (size_t)n * 32 + c) = ov;
        }
        #pragma unroll
        for (int i = 0; i < 32; ++i) {
            int c = (tid + i) & 31;
            atomicAdd(&lsum[b * 32 + c], vals[c]);
            atomicMax(&lmax[b * 32 + c], __float_as_int(vals[c]));
        }
    }
    __syncthreads();
    if (tid < BMAX * 32) {
        atomicAdd(&seg_sum[tid], lsum[tid]);
        atomicMax((int*)(seg_max + tid), lmax[tid]);
    }
}

// ---------------- channel attention
__global__ void k_att(const float* __restrict__ seg_sum, const float* __restrict__ seg_max,
                      const float* __restrict__ cnt, const float* __restrict__ ca1,
                      const float* __restrict__ ca2, float* __restrict__ att)
{
    int b = threadIdx.x >> 6;
    int lane = threadIdx.x & 63;
    bool actc = lane < 32;
    int c = lane & 31;
    float avg = actc ? seg_sum[b * 32 + c] / cnt[b] : 0.f;
    float mx  = actc ? seg_max[b * 32 + c] : 0.f;
    float h[8];
    #pragma unroll
    for (int i = 0; i < 4; ++i) {
        float w = actc ? ca1[c * 4 + i] : 0.f;
        h[i] = avg * w;
        h[i + 4] = mx * w;
    }
    #pragma unroll
    for (int off = 32; off; off >>= 1) {
        #pragma unroll
        for (int i = 0; i < 8; ++i) h[i] += __shfl_xor(h[i], off, 64);
    }
    if (actc) {
        float o = 0.f;
        #pragma unroll
        for (int i = 0; i < 4; ++i)
            o += (fmaxf(h[i], 0.f) + fmaxf(h[i + 4], 0.f)) * ca2[i * 32 + c];
        att[b * 32 + c] = sigmoidf_(o);
    }
}

// ---------------- hatt = h1*att[b] (f32 + bf16 mirror)
__global__ __launch_bounds__(256)
void k_scale_cvt(const float* __restrict__ h1, const float* __restrict__ att,
                 const int* __restrict__ bids, float* __restrict__ hatt,
                 ushort* __restrict__ hattb, int N)
{
    int n = blockIdx.x * 256 + threadIdx.x;
    if (n >= N) return;
    const float* hr = h1 + (size_t)n * 32;
    const float* ar = att + bids[n] * 32;
    float* of = hatt + (size_t)n * 32;
    ushort* ob = hattb + (size_t)n * 32;
    #pragma unroll
    for (int c = 0; c < 32; c += 8) {
        float4 h0 = *(const float4*)(hr + c);
        float4 h1v = *(const float4*)(hr + c + 4);
        float4 a0 = *(const float4*)(ar + c);
        float4 a1 = *(const float4*)(ar + c + 4);
        float g0 = h0.x * a0.x, g1 = h0.y * a0.y, g2 = h0.z * a0.z, g3 = h0.w * a0.w;
        float g4 = h1v.x * a1.x, g5 = h1v.y * a1.y, g6 = h1v.z * a1.z, g7 = h1v.w * a1.w;
        float4 w0; w0.x = g0; w0.y = g1; w0.z = g2; w0.w = g3;
        float4 w1; w1.x = g4; w1.y = g5; w1.z = g6; w1.w = g7;
        *(float4*)(of + c) = w0;
        *(float4*)(of + c + 4) = w1;
        uint4 o; o.x = pk2(g0, g1); o.y = pk2(g2, g3); o.z = pk2(g4, g5); o.w = pk2(g6, g7);
        *(uint4*)(ob + c) = o;
    }
}

// ---------------- h2 = relu(bn(t) + hatt); channel sums for final BN
__global__ __launch_bounds__(256)
void k_comb2(const float* __restrict__ t, const float* __restrict__ hres,
             const float* __restrict__ sc, const float* __restrict__ sh,
             float* __restrict__ hout, float* __restrict__ bnsum,
             float* __restrict__ bnsq, int N)
{
    __shared__ float lsum[32];
    __shared__ float lsq[32];
    int tid = threadIdx.x;
    if (tid < 32) { lsum[tid] = 0.f; lsq[tid] = 0.f; }
    __syncthreads();
    int n = blockIdx.x * 256 + tid;
    bool act = n < N;
    float vals[32];
    if (act) {
        const float* tr = t + (size_t)n * 32;
        const float* hr = hres + (size_t)n * 32;
        #pragma unroll
        for (int c = 0; c < 32; c += 4) {
            float4 tv = *(const float4*)(tr + c);
            float4 hv = *(const float4*)(hr + c);
            vals[c + 0] = fmaxf(tv.x * sc[c + 0] + sh[c + 0] + hv.x, 0.f);
            vals[c + 1] = fmaxf(tv.y * sc[c + 1] + sh[c + 1] + hv.y, 0.f);
            vals[c + 2] = fmaxf(tv.z * sc[c + 2] + sh[c + 2] + hv.z, 0.f);
            vals[c + 3] = fmaxf(tv.w * sc[c + 3] + sh[c + 3] + hv.w, 0.f);
            float4 ov; ov.x = vals[c+0]; ov.y = vals[c+1]; ov.z = vals[c+2]; ov.w = vals[c+3];
            *(float4*)(hout + (size_t)n * 32 + c) = ov;
        }
    } else {
        #pragma unroll
        for (int c = 0; c < 32; ++c) vals[c] = 0.f;
    }
    #pragma unroll
    for (int i = 0; i < 32; ++i) {
        int c = (tid + i) & 31;
        atomicAdd(&lsum[c], vals[c]);
        atomicAdd(&lsq[c], vals[c] * vals[c]);
    }
    __syncthreads();
    if (tid < 32) { atomicAdd(&bnsum[tid], lsum[tid]); atomicAdd(&bnsq[tid], lsq[tid]); }
}

// ---------------- out = relu(bn5(h2)) @ lin_w + lin_b
__global__ __launch_bounds__(256)
void k_final(const float* __restrict__ h2, const float* __restrict__ sc,
             const float* __restrict__ sh, const float* __restrict__ lw,
             const float* __restrict__ lb, float* __restrict__ out, int N)
{
    int n = blockIdx.x * 256 + threadIdx.x;
    if (n >= N) return;
    const float* hr = h2 + (size_t)n * 32;
    float acc[26];
    #pragma unroll
    for (int o = 0; o < 26; ++o) acc[o] = lb[o];
    #pragma unroll
    for (int c4 = 0; c4 < 32; c4 += 4) {
        float4 hv = *(const float4*)(hr + c4);
        float xs[4] = { hv.x, hv.y, hv.z, hv.w };
        #pragma unroll
        for (int cc = 0; cc < 4; ++cc) {
            int c = c4 + cc;
            float x = fmaxf(xs[cc] * sc[c] + sh[c], 0.f);
            const float* wr = lw + c * 26;
            #pragma unroll
            for (int o = 0; o < 26; ++o) acc[o] += x * wr[o];
        }
    }
    float* orow = out + (size_t)n * 26;
    #pragma unroll
    for (int o = 0; o < 26; ++o) orow[o] = acc[o];
}

extern "C" void kernel_launch(void* const* d_in, const int* in_sizes, int n_in,
                              void* d_out, int out_size, void* d_ws, size_t ws_size,
                              hipStream_t stream)
{
    const float* feat_sem = (const float*)d_in[0];
    const float* feat_mos = (const float*)d_in[1];
    const float* fus_sp_w = (const float*)d_in[2];
    const float* fus_sp_b = (const float*)d_in[3];
    const float* fus_ch_w = (const float*)d_in[4];
    const float* fus_ch_b = (const float*)d_in[5];
    const float* conv_w   = (const float*)d_in[6];
    const float* conv_b   = (const float*)d_in[7];
    const float* r1c1_w   = (const float*)d_in[8];
    const float* r1g1     = (const float*)d_in[9];
    const float* r1b1     = (const float*)d_in[10];
    const float* r1c2_w   = (const float*)d_in[11];
    const float* r1g2     = (const float*)d_in[12];
    const float* r1b2     = (const float*)d_in[13];
    const float* ca1_w    = (const float*)d_in[14];
    const float* ca2_w    = (const float*)d_in[15];
    const float* r2c1_w   = (const float*)d_in[16];
    const float* r2g1     = (const float*)d_in[17];
    const float* r2b1     = (const float*)d_in[18];
    const float* r2c2_w   = (const float*)d_in[19];
    const float* r2g2     = (const float*)d_in[20];
    const float* r2b2     = (const float*)d_in[21];
    const float* out_g    = (const float*)d_in[22];
    const float* out_b    = (const float*)d_in[23];
    const float* lin_w    = (const float*)d_in[24];
    const float* lin_b    = (const float*)d_in[25];
    const int*   bids     = (const int*)d_in[26];
    const int*   nbr      = (const int*)d_in[27];
    int N = in_sizes[0] / 64;

    float* ws = (float*)d_ws;
    float* S1 = ws;                              // N*32 f32
    float* S2 = ws + (size_t)32 * N;
    float* S3 = ws + (size_t)64 * N;
    float* S4 = ws + (size_t)96 * N;
    ushort* BB1 = (ushort*)(ws + (size_t)128 * N);   // N*32 bf16
    ushort* BB2 = (ushort*)(ws + (size_t)144 * N);   // N*32 bf16
    float* sbuf = (float*)BB2;                       // s gate (dead before BB2 written)
    ushort* FGB = (ushort*)S3;                       // gated input bf16 N*64 (dead before S3 written)
    float* segpart = S2;                             // 512*256 partials (dead before S2 written)
    float* st = ws + (size_t)160 * N;
    float* seg_fm = st;            // 256
    float* cnt    = st + 256;      // 4
    float* vec    = st + 260;      // 256
    float* bnsum  = st + 516;      // 5*32
    float* bnsq   = st + 676;      // 5*32
    float* bnsc   = st + 836;      // 5*32
    float* bnsh   = st + 996;      // 5*32
    float* seg1s  = st + 1156;     // 128
    float* seg1m  = st + 1284;     // 128
    float* att    = st + 1412;     // 128 (stats end 1540)
    ushort* wpk0 = (ushort*)(st + 1600);   // 27*2*2*64*8 = 55296 ushorts
    ushort* wpk1 = wpk0 + 55296;           // 27648 each
    ushort* wpk2 = wpk1 + 27648;
    ushort* wpk3 = wpk2 + 27648;
    ushort* wpk4 = wpk3 + 27648;

    hipMemsetAsync(st, 0, 1540 * sizeof(float), stream);

    int nb = (N + 255) / 256;
    int nw = (N + 127) / 128;   // mconv: 128 voxels/block
    const int NSEG = 512;
    float invN = 1.f / (float)N;

    k_wpack_all<<<81, 256, 0, stream>>>(conv_w, r1c1_w, r1c2_w, r2c1_w, r2c2_w, wpk0);

    k_fuse_s<<<nb, 256, 0, stream>>>(feat_mos, fus_sp_w, fus_sp_b, bids, sbuf, cnt, N);
    k_seg_part<<<NSEG, 256, 0, stream>>>(feat_sem, sbuf, bids, segpart, N);
    k_seg_red<<<1, 256, 0, stream>>>(segpart, seg_fm, NSEG);
    k_vec<<<1, 256, 0, stream>>>(seg_fm, cnt, fus_ch_w, fus_ch_b, vec);
    k_gate_cvt<<<nb, 256, 0, stream>>>(feat_sem, sbuf, vec, bids, FGB, N);

    k_mconv<64, false, true, true><<<nw, 256, 0, stream>>>(FGB, nbr, wpk0, conv_b,
        S1, BB1, nullptr, nullptr, N);

    k_mconv<32, true, false, false><<<nw, 256, 0, stream>>>(BB1, nbr, wpk1, nullptr,
        S2, nullptr, bnsum + 0, bnsq + 0, N);
    k_stats<<<1, 32, 0, stream>>>(bnsum + 0, bnsq + 0, r1g1, r1b1, bnsc + 0, bnsh + 0, invN);
    k_bnact<<<nb, 256, 0, stream>>>(S2, bnsc + 0, bnsh + 0, BB2, N);

    k_mconv<32, true, false, false><<<nw, 256, 0, stream>>>(BB2, nbr, wpk2, nullptr,
        S3, nullptr, bnsum + 32, bnsq + 32, N);
    k_stats<<<1, 32, 0, stream>>>(bnsum + 32, bnsq + 32, r1g2, r1b2, bnsc + 32, bnsh + 32, invN);

    k_comb1<<<nb, 256, 0, stream>>>(S3, S1, bnsc + 32, bnsh + 32, bids, S4, seg1s, seg1m, N);
    k_att<<<1, 256, 0, stream>>>(seg1s, seg1m, cnt, ca1_w, ca2_w, att);
    k_scale_cvt<<<nb, 256, 0, stream>>>(S4, att, bids, S2, BB1, N);

    k_mconv<32, true, false, false><<<nw, 256, 0, stream>>>(BB1, nbr, wpk3, nullptr,
        S1, nullptr, bnsum + 64, bnsq + 64, N);
    k_stats<<<1, 32, 0, stream>>>(bnsum + 64, bnsq + 64, r2g1, r2b1, bnsc + 64, bnsh + 64, invN);
    k_bnact<<<nb, 256, 0, stream>>>(S1, bnsc + 64, bnsh + 64, BB2, N);

    k_mconv<32, true, false, false><<<nw, 256, 0, stream>>>(BB2, nbr, wpk4, nullptr,
        S3, nullptr, bnsum + 96, bnsq + 96, N);
    k_stats<<<1, 32, 0, stream>>>(bnsum + 96, bnsq + 96, r2g2, r2b2, bnsc + 96, bnsh + 96, invN);

    k_comb2<<<nb, 256, 0, stream>>>(S3, S2, bnsc + 96, bnsh + 96, S4,
        bnsum + 128, bnsq + 128, N);
    k_stats<<<1, 32, 0, stream>>>(bnsum + 128, bnsq + 128, out_g, out_b, bnsc + 128, bnsh + 128, invN);

    k_final<<<nb, 256, 0, stream>>>(S4, bnsc + 128, bnsh + 128, lin_w, lin_b, (float*)d_out, N);
}

// Round 5
// 515.658 us; speedup vs baseline: 2.9804x; 1.1010x over previous
//
#include <hip/hip_runtime.h>
#include <math.h>

#define BMAX 4
typedef __attribute__((ext_vector_type(8))) short s16x8;
typedef __attribute__((ext_vector_type(4))) float f32x4;

__device__ __forceinline__ float sigmoidf_(float x) { return 1.f / (1.f + expf(-x)); }

// f32 -> bf16 RNE
__device__ __forceinline__ ushort f2b(float f) {
    uint u = __float_as_uint(f);
    u = u + 0x7FFFu + ((u >> 16) & 1u);
    return (ushort)(u >> 16);
}
__device__ __forceinline__ uint pk2(float a, float b) {
    return (uint)f2b(a) | ((uint)f2b(b) << 16);
}

// ---------------- fusion gate: s[n] = sigmoid(feat_mos[n].w+b); per-block batch counts
__global__ __launch_bounds__(256)
void k_fuse_s(const float* __restrict__ mos, const float* __restrict__ spw,
              const float* __restrict__ spb, const int* __restrict__ bids,
              float* __restrict__ s_out, float* __restrict__ pc, int N)
{
    __shared__ float lcnt[BMAX];
    int tid = threadIdx.x;
    if (tid < BMAX) lcnt[tid] = 0.f;
    __syncthreads();
    int n = blockIdx.x * 256 + tid;
    if (n < N) {
        const float* mr = mos + (size_t)n * 64;
        float dot = 0.f;
        #pragma unroll
        for (int c = 0; c < 64; c += 4) {
            float4 m4 = *(const float4*)(mr + c);
            float4 w4 = *(const float4*)(spw + c);
            dot += m4.x * w4.x + m4.y * w4.y + m4.z * w4.z + m4.w * w4.w;
        }
        float s = sigmoidf_(dot + spb[0]);
        s_out[n] = s;
        atomicAdd(&lcnt[bids[n]], 1.f);
    }
    __syncthreads();
    if (tid < BMAX) pc[(size_t)blockIdx.x * 4 + tid] = lcnt[tid];
}

// ---------------- stage 1: per-block partial seg-sums of fm = s[n]*feat_sem[n,c]
__global__ __launch_bounds__(256)
void k_seg_part(const float* __restrict__ fsem, const float* __restrict__ s_buf,
                const int* __restrict__ bids, float* __restrict__ part, int N)
{
    __shared__ float lseg[BMAX * 64];
    int tid = threadIdx.x;
    lseg[tid] = 0.f;
    __syncthreads();
    int c = tid & 63;
    int slot = blockIdx.x * 4 + (tid >> 6);
    int nslots = gridDim.x * 4;
    int chunk = (N + nslots - 1) / nslots;
    int n0 = slot * chunk;
    int n1 = min(N, n0 + chunk);
    float acc = 0.f; int curb = -1;
    int n = n0;
    for (; n + 4 <= n1; n += 4) {
        int b0 = bids[n], b3 = bids[n + 3];
        float s0 = s_buf[n], s1 = s_buf[n + 1], s2 = s_buf[n + 2], s3 = s_buf[n + 3];
        float f0 = fsem[(size_t)n * 64 + c];
        float f1 = fsem[(size_t)(n + 1) * 64 + c];
        float f2 = fsem[(size_t)(n + 2) * 64 + c];
        float f3 = fsem[(size_t)(n + 3) * 64 + c];
        if (b0 == b3) {
            if (b0 != curb) {
                if (curb >= 0) atomicAdd(&lseg[curb * 64 + c], acc);
                acc = 0.f; curb = b0;
            }
            acc += s0 * f0 + s1 * f1 + s2 * f2 + s3 * f3;
        } else {
            int bb[4] = { b0, bids[n + 1], bids[n + 2], b3 };
            float sv[4] = { s0, s1, s2, s3 };
            float fv[4] = { f0, f1, f2, f3 };
            #pragma unroll
            for (int q = 0; q < 4; ++q) {
                if (bb[q] != curb) {
                    if (curb >= 0) atomicAdd(&lseg[curb * 64 + c], acc);
                    acc = 0.f; curb = bb[q];
                }
                acc += sv[q] * fv[q];
            }
        }
    }
    for (; n < n1; ++n) {
        int b = bids[n];
        if (b != curb) {
            if (curb >= 0) atomicAdd(&lseg[curb * 64 + c], acc);
            acc = 0.f; curb = b;
        }
        acc += s_buf[n] * fsem[(size_t)n * 64 + c];
    }
    if (curb >= 0) atomicAdd(&lseg[curb * 64 + c], acc);
    __syncthreads();
    part[(size_t)blockIdx.x * 256 + tid] = lseg[tid];
}

// ---------------- stage 2: reduce partials -> seg[256] (1024 threads)
__global__ __launch_bounds__(1024)
void k_seg_red(const float* __restrict__ part, float* __restrict__ seg, int nblk)
{
    __shared__ float l[1024];
    int tid = threadIdx.x;
    int col = tid & 255, grp = tid >> 8;
    float a = 0.f;
    #pragma unroll 8
    for (int j = grp; j < nblk; j += 4) a += part[(size_t)j * 256 + col];
    l[tid] = a;
    __syncthreads();
    if (tid < 256) seg[tid] = l[tid] + l[256 + tid] + l[512 + tid] + l[768 + tid];
}

// ---------------- vec = softmax(seg_mean @ fus_ch_w + b)*64; also reduces counts
__global__ void k_vec(const float* __restrict__ seg, const float* __restrict__ pc, int nbc,
                      const float* __restrict__ chw, const float* __restrict__ chb,
                      float* __restrict__ vec, float* __restrict__ cnt_out)
{
    __shared__ float lred[256];
    __shared__ float lcnt[4];
    int tid = threadIdx.x;
    float a = 0.f;
    for (int j = tid >> 2; j < nbc; j += 64) a += pc[(size_t)j * 4 + (tid & 3)];
    lred[tid] = a;
    __syncthreads();
    if (tid < 4) {
        float s = 0.f;
        #pragma unroll 8
        for (int j = 0; j < 64; ++j) s += lred[j * 4 + tid];
        lcnt[tid] = s;
        cnt_out[tid] = s;
    }
    __syncthreads();
    int b = tid >> 6;
    int c = tid & 63;
    float mean = seg[b * 64 + c] / lcnt[b];
    float v = chb[c];
    #pragma unroll 1
    for (int i = 0; i < 64; ++i) {
        float mi = __shfl(mean, i, 64);
        v += mi * chw[i * 64 + c];
    }
    float m = v;
    #pragma unroll
    for (int off = 32; off; off >>= 1) m = fmaxf(m, __shfl_xor(m, off, 64));
    float e = expf(v - m);
    float ssum = e;
    #pragma unroll
    for (int off = 32; off; off >>= 1) ssum += __shfl_xor(ssum, off, 64);
    vec[b * 64 + c] = e / ssum * 64.f;
}

// ---------------- gated input -> bf16: g = feat_sem * (1 + s*vec[b])
__global__ __launch_bounds__(256)
void k_gate_cvt(const float* __restrict__ fs, const float* __restrict__ s_buf,
                const float* __restrict__ vec, const int* __restrict__ bids,
                ushort* __restrict__ out, int N)
{
    int n = blockIdx.x * 256 + threadIdx.x;
    if (n >= N) return;
    float s = s_buf[n];
    const float* vr = vec + bids[n] * 64;
    const float* fr = fs + (size_t)n * 64;
    ushort* orow = out + (size_t)n * 64;
    #pragma unroll
    for (int c = 0; c < 64; c += 8) {
        float4 f0 = *(const float4*)(fr + c);
        float4 f1 = *(const float4*)(fr + c + 4);
        float4 v0 = *(const float4*)(vr + c);
        float4 v1 = *(const float4*)(vr + c + 4);
        float g0 = f0.x * (1.f + s * v0.x), g1 = f0.y * (1.f + s * v0.y);
        float g2 = f0.z * (1.f + s * v0.z), g3 = f0.w * (1.f + s * v0.w);
        float g4 = f1.x * (1.f + s * v1.x), g5 = f1.y * (1.f + s * v1.y);
        float g6 = f1.z * (1.f + s * v1.z), g7 = f1.w * (1.f + s * v1.w);
        uint4 o; o.x = pk2(g0, g1); o.y = pk2(g2, g3); o.z = pk2(g4, g5); o.w = pk2(g6, g7);
        *(uint4*)(orow + c) = o;
    }
}

// ---------------- pack one weight element into MFMA B-fragment layout
__device__ __forceinline__ void wpack_one(const float* __restrict__ W, int CIN,
                                          int tt, ushort* __restrict__ dst)
{
    int nkc = CIN >> 5;
    int lane = tt & 63;
    int nt = (tt >> 6) & 1;
    int kc = (tt >> 7) % nkc;
    int k = tt / (nkc * 128);
    int kk = kc * 32 + (lane >> 4) * 8;
    int col = nt * 16 + (lane & 15);
    const float* src = W + ((size_t)k * CIN + kk) * 32 + col;
    float v[8];
    #pragma unroll
    for (int e = 0; e < 8; ++e) v[e] = src[e * 32];
    uint4 o; o.x = pk2(v[0], v[1]); o.y = pk2(v[2], v[3]);
    o.z = pk2(v[4], v[5]); o.w = pk2(v[6], v[7]);
    *(uint4*)(dst + (size_t)tt * 8) = o;
}

// ---------------- pack all 5 conv weight tensors in one launch
__global__ __launch_bounds__(256)
void k_wpack_all(const float* __restrict__ W0, const float* __restrict__ W1,
                 const float* __restrict__ W2, const float* __restrict__ W3,
                 const float* __restrict__ W4, ushort* __restrict__ P)
{
    int t = blockIdx.x * 256 + threadIdx.x;
    if (t < 6912) {
        wpack_one(W0, 64, t, P);
    } else {
        int r = t - 6912;
        int s = r / 3456;
        int tt = r % 3456;
        if (s >= 4) return;
        const float* W = (s == 0) ? W1 : (s == 1) ? W2 : (s == 2) ? W3 : W4;
        wpack_one(W, 32, tt, P + 55296 + s * 27648);
    }
}

// ---------------- MFMA gather-conv: wave = 32 voxels (2 M-tiles), 32 out-ch (2 N-tiles)
// STATS: per-block partial sums written to pp[blk*64 + {0..31 sum, 32..63 sq}]
template<int CIN, bool STATS, bool BIAS, bool WB16>
__global__ __launch_bounds__(256)
void k_mconv(const ushort* __restrict__ inb, const int* __restrict__ nbr,
             const ushort* __restrict__ wpk, const float* __restrict__ bias,
             float* __restrict__ outf, ushort* __restrict__ outb,
             float* __restrict__ pp, int N)
{
    __shared__ float lsum[32];
    __shared__ float lsq[32];
    int tid = threadIdx.x;
    if (STATS) {
        if (tid < 32) { lsum[tid] = 0.f; lsq[tid] = 0.f; }
        __syncthreads();
    }
    int lane = tid & 63;
    int gw = (blockIdx.x * 256 + tid) >> 6;
    int vbase = gw * 32;
    bool wact = vbase < N;
    float ps0 = 0.f, pq0 = 0.f, ps1 = 0.f, pq1 = 0.f;
    if (wact) {
        int row = lane & 15;
        int koff = (lane >> 4) * 8;
        f32x4 acc00 = {0.f,0.f,0.f,0.f}, acc01 = {0.f,0.f,0.f,0.f};
        f32x4 acc10 = {0.f,0.f,0.f,0.f}, acc11 = {0.f,0.f,0.f,0.f};
        const int* nb0 = nbr + (size_t)(vbase + row) * 27;
        const int* nb1 = nbr + (size_t)(vbase + 16 + row) * 27;
        #pragma unroll
        for (int k = 0; k < 27; ++k) {
            int j0 = nb0[k];
            int j1 = nb1[k];
            #pragma unroll
            for (int kc = 0; kc < CIN / 32; ++kc) {
                s16x8 a0 = {0,0,0,0,0,0,0,0};
                s16x8 a1 = {0,0,0,0,0,0,0,0};
                if (j0 >= 0) a0 = *(const s16x8*)(inb + (size_t)j0 * CIN + kc * 32 + koff);
                if (j1 >= 0) a1 = *(const s16x8*)(inb + (size_t)j1 * CIN + kc * 32 + koff);
                const ushort* wb = wpk + (size_t)(k * (CIN / 32) + kc) * 1024 + lane * 8;
                s16x8 b0 = *(const s16x8*)(wb);
                s16x8 b1 = *(const s16x8*)(wb + 512);
                acc00 = __builtin_amdgcn_mfma_f32_16x16x32_bf16(a0, b0, acc00, 0, 0, 0);
                acc01 = __builtin_amdgcn_mfma_f32_16x16x32_bf16(a0, b1, acc01, 0, 0, 0);
                acc10 = __builtin_amdgcn_mfma_f32_16x16x32_bf16(a1, b0, acc10, 0, 0, 0);
                acc11 = __builtin_amdgcn_mfma_f32_16x16x32_bf16(a1, b1, acc11, 0, 0, 0);
            }
        }
        int ccol = lane & 15;
        int crow = (lane >> 4) * 4;
        float b0v = BIAS ? bias[ccol] : 0.f;
        float b1v = BIAS ? bias[16 + ccol] : 0.f;
        #pragma unroll
        for (int mt = 0; mt < 2; ++mt) {
            const f32x4& A0 = mt ? acc10 : acc00;
            const f32x4& A1 = mt ? acc11 : acc01;
            #pragma unroll
            for (int i = 0; i < 4; ++i) {
                int v = vbase + mt * 16 + crow + i;
                float x0 = A0[i] + b0v;
                float x1 = A1[i] + b1v;
                outf[(size_t)v * 32 + ccol] = x0;
                outf[(size_t)v * 32 + 16 + ccol] = x1;
                if (WB16) {
                    outb[(size_t)v * 32 + ccol] = f2b(x0);
                    outb[(size_t)v * 32 + 16 + ccol] = f2b(x1);
                }
                if (STATS) { ps0 += x0; pq0 += x0 * x0; ps1 += x1; pq1 += x1 * x1; }
            }
        }
    }
    if (STATS) {
        ps0 += __shfl_xor(ps0, 16, 64); ps0 += __shfl_xor(ps0, 32, 64);
        pq0 += __shfl_xor(pq0, 16, 64); pq0 += __shfl_xor(pq0, 32, 64);
        ps1 += __shfl_xor(ps1, 16, 64); ps1 += __shfl_xor(ps1, 32, 64);
        pq1 += __shfl_xor(pq1, 16, 64); pq1 += __shfl_xor(pq1, 32, 64);
        if (lane < 16) {
            atomicAdd(&lsum[lane], ps0);
            atomicAdd(&lsq[lane], pq0);
            atomicAdd(&lsum[16 + lane], ps1);
            atomicAdd(&lsq[16 + lane], pq1);
        }
        __syncthreads();
        if (tid < 32) {
            pp[(size_t)blockIdx.x * 64 + tid] = lsum[tid];
            pp[(size_t)blockIdx.x * 64 + 32 + tid] = lsq[tid];
        }
    }
}

// ---------------- reduce stats partials [nblk][64] + compute BN scale/shift
__global__ __launch_bounds__(1024)
void k_statsr(const float* __restrict__ part, int nblk,
              const float* __restrict__ g, const float* __restrict__ bb,
              float* __restrict__ sc, float* __restrict__ sh, float invN)
{
    __shared__ float l[1024];
    int tid = threadIdx.x;
    int col = tid & 63, grp = tid >> 6;   // 16 groups
    float a = 0.f;
    #pragma unroll 8
    for (int j = grp; j < nblk; j += 16) a += part[(size_t)j * 64 + col];
    l[tid] = a;
    __syncthreads();
    if (tid < 64) {
        float s = 0.f;
        #pragma unroll
        for (int gq = 0; gq < 16; ++gq) s += l[gq * 64 + tid];
        l[tid] = s;
    }
    __syncthreads();
    if (tid < 32) {
        float m = l[tid] * invN;
        float v = l[32 + tid] * invN - m * m;
        float s = g[tid] * rsqrtf(v + 1e-4f);
        sc[tid] = s;
        sh[tid] = bb[tid] - m * s;
    }
}

// ---------------- a_b = bf16(relu(t*sc+sh))
__global__ __launch_bounds__(256)
void k_bnact(const float* __restrict__ t, const float* __restrict__ sc,
             const float* __restrict__ sh, ushort* __restrict__ out, int N)
{
    int n = blockIdx.x * 256 + threadIdx.x;
    if (n >= N) return;
    const float* tr = t + (size_t)n * 32;
    ushort* orow = out + (size_t)n * 32;
    #pragma unroll
    for (int c = 0; c < 32; c += 8) {
        float4 t0 = *(const float4*)(tr + c);
        float4 t1 = *(const float4*)(tr + c + 4);
        float g0 = fmaxf(t0.x * sc[c+0] + sh[c+0], 0.f);
        float g1 = fmaxf(t0.y * sc[c+1] + sh[c+1], 0.f);
        float g2 = fmaxf(t0.z * sc[c+2] + sh[c+2], 0.f);
        float g3 = fmaxf(t0.w * sc[c+3] + sh[c+3], 0.f);
        float g4 = fmaxf(t1.x * sc[c+4] + sh[c+4], 0.f);
        float g5 = fmaxf(t1.y * sc[c+5] + sh[c+5], 0.f);
        float g6 = fmaxf(t1.z * sc[c+6] + sh[c+6], 0.f);
        float g7 = fmaxf(t1.w * sc[c+7] + sh[c+7], 0.f);
        uint4 o; o.x = pk2(g0, g1); o.y = pk2(g2, g3); o.z = pk2(g4, g5); o.w = pk2(g6, g7);
        *(uint4*)(orow + c) = o;
    }
}

// ---------------- h1 = relu(bn(t)+res); 8ch/thread; per-block (b,c) sum/max partials
// part row layout: [0..127] sums (b*32+c), [128..255] maxes
__global__ __launch_bounds__(256)
void k_comb1(const float* __restrict__ t, const float* __restrict__ res,
             const float* __restrict__ sc, const float* __restrict__ sh,
             const int* __restrict__ bids, float* __restrict__ hout,
             float* __restrict__ part, int N)
{
    __shared__ float lsum[BMAX * 32];
    __shared__ int   lmax[BMAX * 32];
    int tid = threadIdx.x;
    if (tid < BMAX * 32) { lsum[tid] = 0.f; lmax[tid] = 0; }
    __syncthreads();
    int gid = blockIdx.x * 256 + tid;
    int n = gid >> 2;
    int c0 = (gid & 3) * 8;
    if (n < N) {
        int b = bids[n];
        const float* tr = t + (size_t)n * 32 + c0;
        const float* rr = res + (size_t)n * 32 + c0;
        float4 t0 = *(const float4*)tr, t1 = *(const float4*)(tr + 4);
        float4 r0 = *(const float4*)rr, r1 = *(const float4*)(rr + 4);
        float v[8];
        v[0] = fmaxf(t0.x * sc[c0+0] + sh[c0+0] + r0.x, 0.f);
        v[1] = fmaxf(t0.y * sc[c0+1] + sh[c0+1] + r0.y, 0.f);
        v[2] = fmaxf(t0.z * sc[c0+2] + sh[c0+2] + r0.z, 0.f);
        v[3] = fmaxf(t0.w * sc[c0+3] + sh[c0+3] + r0.w, 0.f);
        v[4] = fmaxf(t1.x * sc[c0+4] + sh[c0+4] + r1.x, 0.f);
        v[5] = fmaxf(t1.y * sc[c0+5] + sh[c0+5] + r1.y, 0.f);
        v[6] = fmaxf(t1.z * sc[c0+6] + sh[c0+6] + r1.z, 0.f);
        v[7] = fmaxf(t1.w * sc[c0+7] + sh[c0+7] + r1.w, 0.f);
        float4 o0 = { v[0], v[1], v[2], v[3] };
        float4 o1 = { v[4], v[5], v[6], v[7] };
        *(float4*)(hout + (size_t)n * 32 + c0) = o0;
        *(float4*)(hout + (size_t)n * 32 + c0 + 4) = o1;
        int base = b * 32 + c0;
        #pragma unroll
        for (int i = 0; i < 8; ++i) {
            atomicAdd(&lsum[base + i], v[i]);
            atomicMax(&lmax[base + i], __float_as_int(v[i]));
        }
    }
    __syncthreads();
    if (tid < 128) part[(size_t)blockIdx.x * 256 + tid] = lsum[tid];
    else           part[(size_t)blockIdx.x * 256 + tid] = __int_as_float(lmax[tid - 128]);
}

// ---------------- stage 1 reduce of comb1 partials: [nblk][256] -> [64][256]
__global__ __launch_bounds__(256)
void k_attred(const float* __restrict__ part, int nblk, float* __restrict__ out)
{
    int tid = threadIdx.x;
    int blk = blockIdx.x;
    if (tid < 128) {
        float a = 0.f;
        #pragma unroll 4
        for (int j = blk; j < nblk; j += 64) a += part[(size_t)j * 256 + tid];
        out[(size_t)blk * 256 + tid] = a;
    } else {
        float m = 0.f;
        #pragma unroll 4
        for (int j = blk; j < nblk; j += 64) m = fmaxf(m, part[(size_t)j * 256 + tid]);
        out[(size_t)blk * 256 + tid] = m;
    }
}

// ---------------- channel attention (reduces 64 partial rows, then MLP)
__global__ void k_att(const float* __restrict__ part2, const float* __restrict__ cnt,
                      const float* __restrict__ ca1, const float* __restrict__ ca2,
                      float* __restrict__ att)
{
    __shared__ float seg[256];
    int tid = threadIdx.x;
    if (tid < 128) {
        float a = 0.f;
        #pragma unroll 8
        for (int j = 0; j < 64; ++j) a += part2[j * 256 + tid];
        seg[tid] = a;
    } else {
        float m = 0.f;
        #pragma unroll 8
        for (int j = 0; j < 64; ++j) m = fmaxf(m, part2[j * 256 + tid]);
        seg[tid] = m;
    }
    __syncthreads();
    int b = tid >> 6;
    int lane = tid & 63;
    bool actc = lane < 32;
    int c = lane & 31;
    float avg = actc ? seg[b * 32 + c] / cnt[b] : 0.f;
    float mx  = actc ? seg[128 + b * 32 + c] : 0.f;
    float h[8];
    #pragma unroll
    for (int i = 0; i < 4; ++i) {
        float w = actc ? ca1[c * 4 + i] : 0.f;
        h[i] = avg * w;
        h[i + 4] = mx * w;
    }
    #pragma unroll
    for (int off = 32; off; off >>= 1) {
        #pragma unroll
        for (int i = 0; i < 8; ++i) h[i] += __shfl_xor(h[i], off, 64);
    }
    if (actc) {
        float o = 0.f;
        #pragma unroll
        for (int i = 0; i < 4; ++i)
            o += (fmaxf(h[i], 0.f) + fmaxf(h[i + 4], 0.f)) * ca2[i * 32 + c];
        att[b * 32 + c] = sigmoidf_(o);
    }
}

// ---------------- hatt = h1*att[b] (f32 + bf16 mirror)
__global__ __launch_bounds__(256)
void k_scale_cvt(const float* __restrict__ h1, const float* __restrict__ att,
                 const int* __restrict__ bids, float* __restrict__ hatt,
                 ushort* __restrict__ hattb, int N)
{
    int n = blockIdx.x * 256 + threadIdx.x;
    if (n >= N) return;
    const float* hr = h1 + (size_t)n * 32;
    const float* ar = att + bids[n] * 32;
    float* of = hatt + (size_t)n * 32;
    ushort* ob = hattb + (size_t)n * 32;
    #pragma unroll
    for (int c = 0; c < 32; c += 8) {
        float4 h0 = *(const float4*)(hr + c);
        float4 h1v = *(const float4*)(hr + c + 4);
        float4 a0 = *(const float4*)(ar + c);
        float4 a1 = *(const float4*)(ar + c + 4);
        float g0 = h0.x * a0.x, g1 = h0.y * a0.y, g2 = h0.z * a0.z, g3 = h0.w * a0.w;
        float g4 = h1v.x * a1.x, g5 = h1v.y * a1.y, g6 = h1v.z * a1.z, g7 = h1v.w * a1.w;
        float4 w0; w0.x = g0; w0.y = g1; w0.z = g2; w0.w = g3;
        float4 w1; w1.x = g4; w1.y = g5; w1.z = g6; w1.w = g7;
        *(float4*)(of + c) = w0;
        *(float4*)(of + c + 4) = w1;
        uint4 o; o.x = pk2(g0, g1); o.y = pk2(g2, g3); o.z = pk2(g4, g5); o.w = pk2(g6, g7);
        *(uint4*)(ob + c) = o;
    }
}

// ---------------- h2 = relu(bn(t)+hatt); 8ch/thread; partial sums for final BN
__global__ __launch_bounds__(256)
void k_comb2(const float* __restrict__ t, const float* __restrict__ hres,
             const float* __restrict__ sc, const float* __restrict__ sh,
             float* __restrict__ hout, float* __restrict__ part, int N)
{
    __shared__ float lsum[32];
    __shared__ float lsq[32];
    int tid = threadIdx.x;
    if (tid < 32) { lsum[tid] = 0.f; lsq[tid] = 0.f; }
    __syncthreads();
    int gid = blockIdx.x * 256 + tid;
    int n = gid >> 2;
    int c0 = (gid & 3) * 8;
    if (n < N) {
        const float* tr = t + (size_t)n * 32 + c0;
        const float* hr = hres + (size_t)n * 32 + c0;
        float4 t0 = *(const float4*)tr, t1 = *(const float4*)(tr + 4);
        float4 h0 = *(const float4*)hr, h1 = *(const float4*)(hr + 4);
        float v[8];
        v[0] = fmaxf(t0.x * sc[c0+0] + sh[c0+0] + h0.x, 0.f);
        v[1] = fmaxf(t0.y * sc[c0+1] + sh[c0+1] + h0.y, 0.f);
        v[2] = fmaxf(t0.z * sc[c0+2] + sh[c0+2] + h0.z, 0.f);
        v[3] = fmaxf(t0.w * sc[c0+3] + sh[c0+3] + h0.w, 0.f);
        v[4] = fmaxf(t1.x * sc[c0+4] + sh[c0+4] + h1.x, 0.f);
        v[5] = fmaxf(t1.y * sc[c0+5] + sh[c0+5] + h1.y, 0.f);
        v[6] = fmaxf(t1.z * sc[c0+6] + sh[c0+6] + h1.z, 0.f);
        v[7] = fmaxf(t1.w * sc[c0+7] + sh[c0+7] + h1.w, 0.f);
        float4 o0 = { v[0], v[1], v[2], v[3] };
        float4 o1 = { v[4], v[5], v[6], v[7] };
        *(float4*)(hout + (size_t)n * 32 + c0) = o0;
        *(float4*)(hout + (size_t)n * 32 + c0 + 4) = o1;
        #pragma unroll
        for (int i = 0; i < 8; ++i) {
            atomicAdd(&lsum[c0 + i], v[i]);
            atomicAdd(&lsq[c0 + i], v[i] * v[i]);
        }
    }
    __syncthreads();
    if (tid < 32) {
        part[(size_t)blockIdx.x * 64 + tid] = lsum[tid];
        part[(size_t)blockIdx.x * 64 + 32 + tid] = lsq[tid];
    }
}

// ---------------- out = relu(bn5(h2)) @ lin_w + lin_b
__global__ __launch_bounds__(256)
void k_final(const float* __restrict__ h2, const float* __restrict__ sc,
             const float* __restrict__ sh, const float* __restrict__ lw,
             const float* __restrict__ lb, float* __restrict__ out, int N)
{
    int n = blockIdx.x * 256 + threadIdx.x;
    if (n >= N) return;
    const float* hr = h2 + (size_t)n * 32;
    float acc[26];
    #pragma unroll
    for (int o = 0; o < 26; ++o) acc[o] = lb[o];
    #pragma unroll
    for (int c4 = 0; c4 < 32; c4 += 4) {
        float4 hv = *(const float4*)(hr + c4);
        float xs[4] = { hv.x, hv.y, hv.z, hv.w };
        #pragma unroll
        for (int cc = 0; cc < 4; ++cc) {
            int c = c4 + cc;
            float x = fmaxf(xs[cc] * sc[c] + sh[c], 0.f);
            const float* wr = lw + c * 26;
            #pragma unroll
            for (int o = 0; o < 26; ++o) acc[o] += x * wr[o];
        }
    }
    float* orow = out + (size_t)n * 26;
    #pragma unroll
    for (int o = 0; o < 26; ++o) orow[o] = acc[o];
}

extern "C" void kernel_launch(void* const* d_in, const int* in_sizes, int n_in,
                              void* d_out, int out_size, void* d_ws, size_t ws_size,
                              hipStream_t stream)
{
    const float* feat_sem = (const float*)d_in[0];
    const float* feat_mos = (const float*)d_in[1];
    const float* fus_sp_w = (const float*)d_in[2];
    const float* fus_sp_b = (const float*)d_in[3];
    const float* fus_ch_w = (const float*)d_in[4];
    const float* fus_ch_b = (const float*)d_in[5];
    const float* conv_w   = (const float*)d_in[6];
    const float* conv_b   = (const float*)d_in[7];
    const float* r1c1_w   = (const float*)d_in[8];
    const float* r1g1     = (const float*)d_in[9];
    const float* r1b1     = (const float*)d_in[10];
    const float* r1c2_w   = (const float*)d_in[11];
    const float* r1g2     = (const float*)d_in[12];
    const float* r1b2     = (const float*)d_in[13];
    const float* ca1_w    = (const float*)d_in[14];
    const float* ca2_w    = (const float*)d_in[15];
    const float* r2c1_w   = (const float*)d_in[16];
    const float* r2g1     = (const float*)d_in[17];
    const float* r2b1     = (const float*)d_in[18];
    const float* r2c2_w   = (const float*)d_in[19];
    const float* r2g2     = (const float*)d_in[20];
    const float* r2b2     = (const float*)d_in[21];
    const float* out_g    = (const float*)d_in[22];
    const float* out_b    = (const float*)d_in[23];
    const float* lin_w    = (const float*)d_in[24];
    const float* lin_b    = (const float*)d_in[25];
    const int*   bids     = (const int*)d_in[26];
    const int*   nbr      = (const int*)d_in[27];
    int N = in_sizes[0] / 64;

    float* ws = (float*)d_ws;
    float* S1 = ws;                              // N*32 f32 regions
    float* S2 = ws + (size_t)32 * N;
    float* S3 = ws + (size_t)64 * N;
    float* S4 = ws + (size_t)96 * N;
    ushort* BB1 = (ushort*)(ws + (size_t)128 * N);   // N*32 bf16
    ushort* BB2 = (ushort*)(ws + (size_t)144 * N);   // N*32 bf16
    float* sbuf = (float*)BB2;                       // alias: dead before BB2 written
    ushort* FGB = (ushort*)S3;                       // alias: dead before S3 written
    float* segpart = S2;                             // alias: dead before S2 written
    float* st = ws + (size_t)160 * N;
    float* seg_fm = st;              // 256
    float* cnt    = st + 256;        // 4
    float* vec    = st + 260;        // 256 (ends 516)
    float* bnsc   = st + 516;        // 5*32 (ends 676)
    float* bnsh   = st + 676;        // 5*32 (ends 836)
    float* attbuf = st + 840;        // 128 (ends 968)
    float* pcnt   = st + 2048;       // up to 2048 (ends 4096)
    float* at2    = st + 4096;       // 64*256 (ends 20480)
    ushort* wpk0 = (ushort*)(st + 20480);  // 55296 ushorts
    ushort* wpk1 = wpk0 + 55296;           // 27648 each
    ushort* wpk2 = wpk1 + 27648;
    ushort* wpk3 = wpk2 + 27648;
    ushort* wpk4 = wpk3 + 27648;

    int nb  = (N + 255) / 256;
    int nw  = (N + 127) / 128;   // mconv: 128 voxels/block
    int nb4 = (N + 63) / 64;     // comb: 8ch/thread
    const int NSEG = 512;
    float invN = 1.f / (float)N;

    k_wpack_all<<<81, 256, 0, stream>>>(conv_w, r1c1_w, r1c2_w, r2c1_w, r2c2_w, wpk0);

    k_fuse_s<<<nb, 256, 0, stream>>>(feat_mos, fus_sp_w, fus_sp_b, bids, sbuf, pcnt, N);
    k_seg_part<<<NSEG, 256, 0, stream>>>(feat_sem, sbuf, bids, segpart, N);
    k_seg_red<<<1, 1024, 0, stream>>>(segpart, seg_fm, NSEG);
    k_vec<<<1, 256, 0, stream>>>(seg_fm, pcnt, nb, fus_ch_w, fus_ch_b, vec, cnt);
    k_gate_cvt<<<nb, 256, 0, stream>>>(feat_sem, sbuf, vec, bids, FGB, N);

    k_mconv<64, false, true, true><<<nw, 256, 0, stream>>>(FGB, nbr, wpk0, conv_b,
        S1, BB1, nullptr, N);

    k_mconv<32, true, false, false><<<nw, 256, 0, stream>>>(BB1, nbr, wpk1, nullptr,
        S2, nullptr, S4, N);
    k_statsr<<<1, 1024, 0, stream>>>(S4, nw, r1g1, r1b1, bnsc + 0, bnsh + 0, invN);
    k_bnact<<<nb, 256, 0, stream>>>(S2, bnsc + 0, bnsh + 0, BB2, N);

    k_mconv<32, true, false, false><<<nw, 256, 0, stream>>>(BB2, nbr, wpk2, nullptr,
        S3, nullptr, S4, N);
    k_statsr<<<1, 1024, 0, stream>>>(S4, nw, r1g2, r1b2, bnsc + 32, bnsh + 32, invN);

    k_comb1<<<nb4, 256, 0, stream>>>(S3, S1, bnsc + 32, bnsh + 32, bids, S4, S2, N);
    k_attred<<<64, 256, 0, stream>>>(S2, nb4, at2);
    k_att<<<1, 256, 0, stream>>>(at2, cnt, ca1_w, ca2_w, attbuf);
    k_scale_cvt<<<nb, 256, 0, stream>>>(S4, attbuf, bids, S2, BB1, N);

    k_mconv<32, true, false, false><<<nw, 256, 0, stream>>>(BB1, nbr, wpk3, nullptr,
        S1, nullptr, S3, N);
    k_statsr<<<1, 1024, 0, stream>>>(S3, nw, r2g1, r2b1, bnsc + 64, bnsh + 64, invN);
    k_bnact<<<nb, 256, 0, stream>>>(S1, bnsc + 64, bnsh + 64, BB2, N);

    k_mconv<32, true, false, false><<<nw, 256, 0, stream>>>(BB2, nbr, wpk4, nullptr,
        S3, nullptr, S4, N);
    k_statsr<<<1, 1024, 0, stream>>>(S4, nw, r2g2, r2b2, bnsc + 96, bnsh + 96, invN);

    k_comb2<<<nb4, 256, 0, stream>>>(S3, S2, bnsc + 96, bnsh + 96, S1, S4, N);
    k_statsr<<<1, 1024, 0, stream>>>(S4, nb4, out_g, out_b, bnsc + 128, bnsh + 128, invN);

    k_final<<<nb, 256, 0, stream>>>(S1, bnsc + 128, bnsh + 128, lin_w, lin_b, (float*)d_out, N);
}

// Round 7
// 491.610 us; speedup vs baseline: 3.1262x; 1.0489x over previous
//
#include <hip/hip_runtime.h>
#include <math.h>

#define BMAX 4
typedef __attribute__((ext_vector_type(8))) short s16x8;
typedef __attribute__((ext_vector_type(4))) float f32x4;

__device__ __forceinline__ float sigmoidf_(float x) { return 1.f / (1.f + expf(-x)); }

// f32 -> bf16 RNE
__device__ __forceinline__ ushort f2b(float f) {
    uint u = __float_as_uint(f);
    u = u + 0x7FFFu + ((u >> 16) & 1u);
    return (ushort)(u >> 16);
}
__device__ __forceinline__ uint pk2(float a, float b) {
    return (uint)f2b(a) | ((uint)f2b(b) << 16);
}

// ---------------- transpose nbr [N][27] -> nbrT [27][N] (LDS-tiled, coalesced both sides)
__global__ __launch_bounds__(256)
void k_nbrT(const int* __restrict__ nbr, int* __restrict__ nbrT, int N)
{
    __shared__ int l[64 * 27];
    int tid = threadIdx.x;
    int n0 = blockIdx.x * 64;
    int nrows = min(64, N - n0);
    int tot = nrows * 27;
    for (int t = tid; t < tot; t += 256) l[t] = nbr[(size_t)n0 * 27 + t];
    __syncthreads();
    int lane = tid & 63;
    if (lane < nrows) {
        for (int k = tid >> 6; k < 27; k += 4)
            nbrT[(size_t)k * N + n0 + lane] = l[lane * 27 + k];
    }
}

// ---------------- fusion gate: s[n] = sigmoid(feat_mos[n].w+b); per-block batch counts
__global__ __launch_bounds__(256)
void k_fuse_s(const float* __restrict__ mos, const float* __restrict__ spw,
              const float* __restrict__ spb, const int* __restrict__ bids,
              float* __restrict__ s_out, float* __restrict__ pc, int N)
{
    __shared__ float lcnt[BMAX];
    int tid = threadIdx.x;
    if (tid < BMAX) lcnt[tid] = 0.f;
    __syncthreads();
    int n = blockIdx.x * 256 + tid;
    if (n < N) {
        const float* mr = mos + (size_t)n * 64;
        float dot = 0.f;
        #pragma unroll
        for (int c = 0; c < 64; c += 4) {
            float4 m4 = *(const float4*)(mr + c);
            float4 w4 = *(const float4*)(spw + c);
            dot += m4.x * w4.x + m4.y * w4.y + m4.z * w4.z + m4.w * w4.w;
        }
        float s = sigmoidf_(dot + spb[0]);
        s_out[n] = s;
        atomicAdd(&lcnt[bids[n]], 1.f);
    }
    __syncthreads();
    if (tid < BMAX) pc[(size_t)blockIdx.x * 4 + tid] = lcnt[tid];
}

// ---------------- stage 1: per-block partial seg-sums of fm = s[n]*feat_sem[n,c]
__global__ __launch_bounds__(256)
void k_seg_part(const float* __restrict__ fsem, const float* __restrict__ s_buf,
                const int* __restrict__ bids, float* __restrict__ part, int N)
{
    __shared__ float lseg[BMAX * 64];
    int tid = threadIdx.x;
    lseg[tid] = 0.f;
    __syncthreads();
    int c = tid & 63;
    int slot = blockIdx.x * 4 + (tid >> 6);
    int nslots = gridDim.x * 4;
    int chunk = (N + nslots - 1) / nslots;
    int n0 = slot * chunk;
    int n1 = min(N, n0 + chunk);
    float acc = 0.f; int curb = -1;
    int n = n0;
    for (; n + 4 <= n1; n += 4) {
        int b0 = bids[n], b3 = bids[n + 3];
        float s0 = s_buf[n], s1 = s_buf[n + 1], s2 = s_buf[n + 2], s3 = s_buf[n + 3];
        float f0 = fsem[(size_t)n * 64 + c];
        float f1 = fsem[(size_t)(n + 1) * 64 + c];
        float f2 = fsem[(size_t)(n + 2) * 64 + c];
        float f3 = fsem[(size_t)(n + 3) * 64 + c];
        if (b0 == b3) {
            if (b0 != curb) {
                if (curb >= 0) atomicAdd(&lseg[curb * 64 + c], acc);
                acc = 0.f; curb = b0;
            }
            acc += s0 * f0 + s1 * f1 + s2 * f2 + s3 * f3;
        } else {
            int bb[4] = { b0, bids[n + 1], bids[n + 2], b3 };
            float sv[4] = { s0, s1, s2, s3 };
            float fv[4] = { f0, f1, f2, f3 };
            #pragma unroll
            for (int q = 0; q < 4; ++q) {
                if (bb[q] != curb) {
                    if (curb >= 0) atomicAdd(&lseg[curb * 64 + c], acc);
                    acc = 0.f; curb = bb[q];
                }
                acc += sv[q] * fv[q];
            }
        }
    }
    for (; n < n1; ++n) {
        int b = bids[n];
        if (b != curb) {
            if (curb >= 0) atomicAdd(&lseg[curb * 64 + c], acc);
            acc = 0.f; curb = b;
        }
        acc += s_buf[n] * fsem[(size_t)n * 64 + c];
    }
    if (curb >= 0) atomicAdd(&lseg[curb * 64 + c], acc);
    __syncthreads();
    part[(size_t)blockIdx.x * 256 + tid] = lseg[tid];
}

// ---------------- stage 2: reduce partials -> seg[256]
__global__ __launch_bounds__(1024)
void k_seg_red(const float* __restrict__ part, float* __restrict__ seg, int nblk)
{
    __shared__ float l[1024];
    int tid = threadIdx.x;
    int col = tid & 255, grp = tid >> 8;
    float a = 0.f;
    #pragma unroll 8
    for (int j = grp; j < nblk; j += 4) a += part[(size_t)j * 256 + col];
    l[tid] = a;
    __syncthreads();
    if (tid < 256) seg[tid] = l[tid] + l[256 + tid] + l[512 + tid] + l[768 + tid];
}

// ---------------- vec = softmax(seg_mean @ fus_ch_w + b)*64; also reduces counts
__global__ void k_vec(const float* __restrict__ seg, const float* __restrict__ pc, int nbc,
                      const float* __restrict__ chw, const float* __restrict__ chb,
                      float* __restrict__ vec, float* __restrict__ cnt_out)
{
    __shared__ float lred[256];
    __shared__ float lcnt[4];
    int tid = threadIdx.x;
    float a = 0.f;
    for (int j = tid >> 2; j < nbc; j += 64) a += pc[(size_t)j * 4 + (tid & 3)];
    lred[tid] = a;
    __syncthreads();
    if (tid < 4) {
        float s = 0.f;
        #pragma unroll 8
        for (int j = 0; j < 64; ++j) s += lred[j * 4 + tid];
        lcnt[tid] = s;
        cnt_out[tid] = s;
    }
    __syncthreads();
    int b = tid >> 6;
    int c = tid & 63;
    float mean = seg[b * 64 + c] / lcnt[b];
    float v = chb[c];
    #pragma unroll 1
    for (int i = 0; i < 64; ++i) {
        float mi = __shfl(mean, i, 64);
        v += mi * chw[i * 64 + c];
    }
    float m = v;
    #pragma unroll
    for (int off = 32; off; off >>= 1) m = fmaxf(m, __shfl_xor(m, off, 64));
    float e = expf(v - m);
    float ssum = e;
    #pragma unroll
    for (int off = 32; off; off >>= 1) ssum += __shfl_xor(ssum, off, 64);
    vec[b * 64 + c] = e / ssum * 64.f;
}

// ---------------- gated input -> bf16 (8 thr/voxel); writes zero row N
__global__ __launch_bounds__(256)
void k_gate_cvt(const float* __restrict__ fs, const float* __restrict__ s_buf,
                const float* __restrict__ vec, const int* __restrict__ bids,
                ushort* __restrict__ out, int N)
{
    int gid = blockIdx.x * 256 + threadIdx.x;
    if (gid < 64) out[(size_t)N * 64 + gid] = 0;
    int n = gid >> 3;
    if (n >= N) return;
    int c0 = (gid & 7) * 8;
    float s = s_buf[n];
    const float* vr = vec + bids[n] * 64 + c0;
    const float* fr = fs + (size_t)n * 64 + c0;
    float4 f0 = *(const float4*)fr, f1 = *(const float4*)(fr + 4);
    float4 v0 = *(const float4*)vr, v1 = *(const float4*)(vr + 4);
    float g0 = f0.x * (1.f + s * v0.x), g1 = f0.y * (1.f + s * v0.y);
    float g2 = f0.z * (1.f + s * v0.z), g3 = f0.w * (1.f + s * v0.w);
    float g4 = f1.x * (1.f + s * v1.x), g5 = f1.y * (1.f + s * v1.y);
    float g6 = f1.z * (1.f + s * v1.z), g7 = f1.w * (1.f + s * v1.w);
    uint4 o; o.x = pk2(g0, g1); o.y = pk2(g2, g3); o.z = pk2(g4, g5); o.w = pk2(g6, g7);
    *(uint4*)(out + (size_t)n * 64 + c0) = o;
}

// ---------------- pack one weight element into MFMA B-fragment layout
__device__ __forceinline__ void wpack_one(const float* __restrict__ W, int CIN,
                                          int tt, ushort* __restrict__ dst)
{
    int nkc = CIN >> 5;
    int lane = tt & 63;
    int nt = (tt >> 6) & 1;
    int kc = (tt >> 7) % nkc;
    int k = tt / (nkc * 128);
    int kk = kc * 32 + (lane >> 4) * 8;
    int col = nt * 16 + (lane & 15);
    const float* src = W + ((size_t)k * CIN + kk) * 32 + col;
    float v[8];
    #pragma unroll
    for (int e = 0; e < 8; ++e) v[e] = src[e * 32];
    uint4 o; o.x = pk2(v[0], v[1]); o.y = pk2(v[2], v[3]);
    o.z = pk2(v[4], v[5]); o.w = pk2(v[6], v[7]);
    *(uint4*)(dst + (size_t)tt * 8) = o;
}

__global__ __launch_bounds__(256)
void k_wpack_all(const float* __restrict__ W0, const float* __restrict__ W1,
                 const float* __restrict__ W2, const float* __restrict__ W3,
                 const float* __restrict__ W4, ushort* __restrict__ P)
{
    int t = blockIdx.x * 256 + threadIdx.x;
    if (t < 6912) {
        wpack_one(W0, 64, t, P);
    } else {
        int r = t - 6912;
        int s = r / 3456;
        int tt = r % 3456;
        if (s >= 4) return;
        const float* W = (s == 0) ? W1 : (s == 1) ? W2 : (s == 2) ? W3 : W4;
        wpack_one(W, 32, tt, P + 55296 + s * 27648);
    }
}

// ---------------- MFMA gather-conv: wave = 16 voxels (1 M-tile), 32 out-ch (2 N-tiles)
// branchless zero-page gathers (row N of inb is zeros), transposed nbrT index loads
template<int CIN, bool STATS, bool BIAS, bool WB16>
__global__ __launch_bounds__(256)
void k_mconv(const ushort* __restrict__ inb, const int* __restrict__ nbrT,
             const ushort* __restrict__ wpk, const float* __restrict__ bias,
             float* __restrict__ outf, ushort* __restrict__ outb,
             float* __restrict__ pp, int N)
{
    __shared__ float lsum[32];
    __shared__ float lsq[32];
    int tid = threadIdx.x;
    if (WB16 && blockIdx.x == 0 && tid < 32) outb[(size_t)N * 32 + tid] = 0;
    if (STATS) {
        if (tid < 32) { lsum[tid] = 0.f; lsq[tid] = 0.f; }
        __syncthreads();
    }
    int lane = tid & 63;
    int gw = (blockIdx.x * 256 + tid) >> 6;
    int vbase = gw * 16;
    float ps0 = 0.f, pq0 = 0.f, ps1 = 0.f, pq1 = 0.f;
    if (vbase < N) {
        int row = lane & 15;
        int koff = (lane >> 4) * 8;
        int vr = vbase + row; if (vr >= N) vr = N - 1;
        f32x4 acc0 = {0.f,0.f,0.f,0.f}, acc1 = {0.f,0.f,0.f,0.f};
        int j[27];
        #pragma unroll
        for (int k = 0; k < 27; ++k) j[k] = nbrT[(size_t)k * N + vr];
        #pragma unroll
        for (int k = 0; k < 27; ++k) {
            int jj = (j[k] < 0) ? N : j[k];
            const ushort* arow = inb + (size_t)jj * CIN + koff;
            #pragma unroll
            for (int kc = 0; kc < CIN / 32; ++kc) {
                s16x8 a = *(const s16x8*)(arow + kc * 32);
                const ushort* wb = wpk + (size_t)(k * (CIN / 32) + kc) * 1024 + lane * 8;
                s16x8 b0 = *(const s16x8*)(wb);
                s16x8 b1 = *(const s16x8*)(wb + 512);
                acc0 = __builtin_amdgcn_mfma_f32_16x16x32_bf16(a, b0, acc0, 0, 0, 0);
                acc1 = __builtin_amdgcn_mfma_f32_16x16x32_bf16(a, b1, acc1, 0, 0, 0);
            }
        }
        int ccol = lane & 15;
        int crow = (lane >> 4) * 4;
        float b0v = BIAS ? bias[ccol] : 0.f;
        float b1v = BIAS ? bias[16 + ccol] : 0.f;
        #pragma unroll
        for (int i = 0; i < 4; ++i) {
            int v = vbase + crow + i;
            if (v < N) {
                float x0 = acc0[i] + b0v;
                float x1 = acc1[i] + b1v;
                outf[(size_t)v * 32 + ccol] = x0;
                outf[(size_t)v * 32 + 16 + ccol] = x1;
                if (WB16) {
                    outb[(size_t)v * 32 + ccol] = f2b(x0);
                    outb[(size_t)v * 32 + 16 + ccol] = f2b(x1);
                }
                if (STATS) { ps0 += x0; pq0 += x0 * x0; ps1 += x1; pq1 += x1 * x1; }
            }
        }
    }
    if (STATS) {
        ps0 += __shfl_xor(ps0, 16, 64); ps0 += __shfl_xor(ps0, 32, 64);
        pq0 += __shfl_xor(pq0, 16, 64); pq0 += __shfl_xor(pq0, 32, 64);
        ps1 += __shfl_xor(ps1, 16, 64); ps1 += __shfl_xor(ps1, 32, 64);
        pq1 += __shfl_xor(pq1, 16, 64); pq1 += __shfl_xor(pq1, 32, 64);
        if (lane < 16) {
            atomicAdd(&lsum[lane], ps0);
            atomicAdd(&lsq[lane], pq0);
            atomicAdd(&lsum[16 + lane], ps1);
            atomicAdd(&lsq[16 + lane], pq1);
        }
        __syncthreads();
        if (tid < 32) {
            pp[(size_t)blockIdx.x * 64 + tid] = lsum[tid];
            pp[(size_t)blockIdx.x * 64 + 32 + tid] = lsq[tid];
        }
    }
}

// ---------------- reduce stats partials [nblk][64] + compute BN scale/shift
__global__ __launch_bounds__(1024)
void k_statsr(const float* __restrict__ part, int nblk,
              const float* __restrict__ g, const float* __restrict__ bb,
              float* __restrict__ sc, float* __restrict__ sh, float invN)
{
    __shared__ float l[1024];
    int tid = threadIdx.x;
    int col = tid & 63, grp = tid >> 6;
    float a = 0.f;
    #pragma unroll 8
    for (int j = grp; j < nblk; j += 16) a += part[(size_t)j * 64 + col];
    l[tid] = a;
    __syncthreads();
    if (tid < 64) {
        float s = 0.f;
        #pragma unroll
        for (int gq = 0; gq < 16; ++gq) s += l[gq * 64 + tid];
        l[tid] = s;
    }
    __syncthreads();
    if (tid < 32) {
        float m = l[tid] * invN;
        float v = l[32 + tid] * invN - m * m;
        float s = g[tid] * rsqrtf(v + 1e-4f);
        sc[tid] = s;
        sh[tid] = bb[tid] - m * s;
    }
}

// ---------------- a_b = bf16(relu(t*sc+sh)) (4 thr/voxel); writes zero row N
__global__ __launch_bounds__(256)
void k_bnact(const float* __restrict__ t, const float* __restrict__ sc,
             const float* __restrict__ sh, ushort* __restrict__ out, int N)
{
    int gid = blockIdx.x * 256 + threadIdx.x;
    if (gid < 32) out[(size_t)N * 32 + gid] = 0;
    int n = gid >> 2;
    if (n >= N) return;
    int c0 = (gid & 3) * 8;
    const float* tr = t + (size_t)n * 32 + c0;
    float4 t0 = *(const float4*)tr, t1 = *(const float4*)(tr + 4);
    float g0 = fmaxf(t0.x * sc[c0+0] + sh[c0+0], 0.f);
    float g1 = fmaxf(t0.y * sc[c0+1] + sh[c0+1], 0.f);
    float g2 = fmaxf(t0.z * sc[c0+2] + sh[c0+2], 0.f);
    float g3 = fmaxf(t0.w * sc[c0+3] + sh[c0+3], 0.f);
    float g4 = fmaxf(t1.x * sc[c0+4] + sh[c0+4], 0.f);
    float g5 = fmaxf(t1.y * sc[c0+5] + sh[c0+5], 0.f);
    float g6 = fmaxf(t1.z * sc[c0+6] + sh[c0+6], 0.f);
    float g7 = fmaxf(t1.w * sc[c0+7] + sh[c0+7], 0.f);
    uint4 o; o.x = pk2(g0, g1); o.y = pk2(g2, g3); o.z = pk2(g4, g5); o.w = pk2(g6, g7);
    *(uint4*)(out + (size_t)n * 32 + c0) = o;
}

// ---------------- h1 = relu(bn(t)+h) IN-PLACE on hr; per-block (b,c) sum/max partials
__global__ __launch_bounds__(256)
void k_comb1(const float* __restrict__ t, const float* __restrict__ sc,
             const float* __restrict__ sh, const int* __restrict__ bids,
             float* hr, float* __restrict__ part, int N)
{
    __shared__ float lsum[BMAX * 32];
    __shared__ int   lmax[BMAX * 32];
    int tid = threadIdx.x;
    if (tid < BMAX * 32) { lsum[tid] = 0.f; lmax[tid] = 0; }
    __syncthreads();
    int gid = blockIdx.x * 256 + tid;
    int n = gid >> 2;
    int c0 = (gid & 3) * 8;
    if (n < N) {
        int b = bids[n];
        const float* tr = t + (size_t)n * 32 + c0;
        float* rr = hr + (size_t)n * 32 + c0;
        float4 t0 = *(const float4*)tr, t1 = *(const float4*)(tr + 4);
        float4 r0 = *(const float4*)rr, r1 = *(const float4*)(rr + 4);
        float v[8];
        v[0] = fmaxf(t0.x * sc[c0+0] + sh[c0+0] + r0.x, 0.f);
        v[1] = fmaxf(t0.y * sc[c0+1] + sh[c0+1] + r0.y, 0.f);
        v[2] = fmaxf(t0.z * sc[c0+2] + sh[c0+2] + r0.z, 0.f);
        v[3] = fmaxf(t0.w * sc[c0+3] + sh[c0+3] + r0.w, 0.f);
        v[4] = fmaxf(t1.x * sc[c0+4] + sh[c0+4] + r1.x, 0.f);
        v[5] = fmaxf(t1.y * sc[c0+5] + sh[c0+5] + r1.y, 0.f);
        v[6] = fmaxf(t1.z * sc[c0+6] + sh[c0+6] + r1.z, 0.f);
        v[7] = fmaxf(t1.w * sc[c0+7] + sh[c0+7] + r1.w, 0.f);
        float4 o0 = { v[0], v[1], v[2], v[3] };
        float4 o1 = { v[4], v[5], v[6], v[7] };
        *(float4*)rr = o0;
        *(float4*)(rr + 4) = o1;
        int base = b * 32 + c0;
        #pragma unroll
        for (int i = 0; i < 8; ++i) {
            atomicAdd(&lsum[base + i], v[i]);
            atomicMax(&lmax[base + i], __float_as_int(v[i]));
        }
    }
    __syncthreads();
    if (tid < 128) part[(size_t)blockIdx.x * 256 + tid] = lsum[tid];
    else           part[(size_t)blockIdx.x * 256 + tid] = __int_as_float(lmax[tid - 128]);
}

// ---------------- stage 1 reduce of comb1 partials: [nblk][256] -> [64][256]
__global__ __launch_bounds__(256)
void k_attred(const float* __restrict__ part, int nblk, float* __restrict__ out)
{
    int tid = threadIdx.x;
    int blk = blockIdx.x;
    if (tid < 128) {
        float a = 0.f;
        #pragma unroll 4
        for (int j = blk; j < nblk; j += 64) a += part[(size_t)j * 256 + tid];
        out[(size_t)blk * 256 + tid] = a;
    } else {
        float m = 0.f;
        #pragma unroll 4
        for (int j = blk; j < nblk; j += 64) m = fmaxf(m, part[(size_t)j * 256 + tid]);
        out[(size_t)blk * 256 + tid] = m;
    }
}

// ---------------- channel attention
__global__ void k_att(const float* __restrict__ part2, const float* __restrict__ cnt,
                      const float* __restrict__ ca1, const float* __restrict__ ca2,
                      float* __restrict__ att)
{
    __shared__ float seg[256];
    int tid = threadIdx.x;
    if (tid < 128) {
        float a = 0.f;
        #pragma unroll 8
        for (int j = 0; j < 64; ++j) a += part2[j * 256 + tid];
        seg[tid] = a;
    } else {
        float m = 0.f;
        #pragma unroll 8
        for (int j = 0; j < 64; ++j) m = fmaxf(m, part2[j * 256 + tid]);
        seg[tid] = m;
    }
    __syncthreads();
    int b = tid >> 6;
    int lane = tid & 63;
    bool actc = lane < 32;
    int c = lane & 31;
    float avg = actc ? seg[b * 32 + c] / cnt[b] : 0.f;
    float mx  = actc ? seg[128 + b * 32 + c] : 0.f;
    float h[8];
    #pragma unroll
    for (int i = 0; i < 4; ++i) {
        float w = actc ? ca1[c * 4 + i] : 0.f;
        h[i] = avg * w;
        h[i + 4] = mx * w;
    }
    #pragma unroll
    for (int off = 32; off; off >>= 1) {
        #pragma unroll
        for (int i = 0; i < 8; ++i) h[i] += __shfl_xor(h[i], off, 64);
    }
    if (actc) {
        float o = 0.f;
        #pragma unroll
        for (int i = 0; i < 4; ++i)
            o += (fmaxf(h[i], 0.f) + fmaxf(h[i + 4], 0.f)) * ca2[i * 32 + c];
        att[b * 32 + c] = sigmoidf_(o);
    }
}

// ---------------- hatt = h1*att[b] (4 thr/voxel); f32 + bf16 mirror; zero row N of bf16
__global__ __launch_bounds__(256)
void k_scale_cvt(const float* __restrict__ h1, const float* __restrict__ att,
                 const int* __restrict__ bids, float* __restrict__ hatt,
                 ushort* __restrict__ hattb, int N)
{
    int gid = blockIdx.x * 256 + threadIdx.x;
    if (gid < 32) hattb[(size_t)N * 32 + gid] = 0;
    int n = gid >> 2;
    if (n >= N) return;
    int c0 = (gid & 3) * 8;
    const float* hrp = h1 + (size_t)n * 32 + c0;
    const float* ar = att + bids[n] * 32 + c0;
    float4 h0 = *(const float4*)hrp, h1v = *(const float4*)(hrp + 4);
    float4 a0 = *(const float4*)ar, a1 = *(const float4*)(ar + 4);
    float g0 = h0.x * a0.x, g1 = h0.y * a0.y, g2 = h0.z * a0.z, g3 = h0.w * a0.w;
    float g4 = h1v.x * a1.x, g5 = h1v.y * a1.y, g6 = h1v.z * a1.z, g7 = h1v.w * a1.w;
    float4 w0 = { g0, g1, g2, g3 };
    float4 w1 = { g4, g5, g6, g7 };
    *(float4*)(hatt + (size_t)n * 32 + c0) = w0;
    *(float4*)(hatt + (size_t)n * 32 + c0 + 4) = w1;
    uint4 o; o.x = pk2(g0, g1); o.y = pk2(g2, g3); o.z = pk2(g4, g5); o.w = pk2(g6, g7);
    *(uint4*)(hattb + (size_t)n * 32 + c0) = o;
}

// ---------------- h2 = relu(bn(t)+hres) IN-PLACE on hr; partial sums for final BN
__global__ __launch_bounds__(256)
void k_comb2(const float* __restrict__ t, const float* __restrict__ sc,
             const float* __restrict__ sh, float* hr, float* __restrict__ part, int N)
{
    __shared__ float lsum[32];
    __shared__ float lsq[32];
    int tid = threadIdx.x;
    if (tid < 32) { lsum[tid] = 0.f; lsq[tid] = 0.f; }
    __syncthreads();
    int gid = blockIdx.x * 256 + tid;
    int n = gid >> 2;
    int c0 = (gid & 3) * 8;
    if (n < N) {
        const float* tr = t + (size_t)n * 32 + c0;
        float* rr = hr + (size_t)n * 32 + c0;
        float4 t0 = *(const float4*)tr, t1 = *(const float4*)(tr + 4);
        float4 h0 = *(const float4*)rr, h1 = *(const float4*)(rr + 4);
        float v[8];
        v[0] = fmaxf(t0.x * sc[c0+0] + sh[c0+0] + h0.x, 0.f);
        v[1] = fmaxf(t0.y * sc[c0+1] + sh[c0+1] + h0.y, 0.f);
        v[2] = fmaxf(t0.z * sc[c0+2] + sh[c0+2] + h0.z, 0.f);
        v[3] = fmaxf(t0.w * sc[c0+3] + sh[c0+3] + h0.w, 0.f);
        v[4] = fmaxf(t1.x * sc[c0+4] + sh[c0+4] + h1.x, 0.f);
        v[5] = fmaxf(t1.y * sc[c0+5] + sh[c0+5] + h1.y, 0.f);
        v[6] = fmaxf(t1.z * sc[c0+6] + sh[c0+6] + h1.z, 0.f);
        v[7] = fmaxf(t1.w * sc[c0+7] + sh[c0+7] + h1.w, 0.f);
        float4 o0 = { v[0], v[1], v[2], v[3] };
        float4 o1 = { v[4], v[5], v[6], v[7] };
        *(float4*)rr = o0;
        *(float4*)(rr + 4) = o1;
        #pragma unroll
        for (int i = 0; i < 8; ++i) {
            atomicAdd(&lsum[c0 + i], v[i]);
            atomicAdd(&lsq[c0 + i], v[i] * v[i]);
        }
    }
    __syncthreads();
    if (tid < 32) {
        part[(size_t)blockIdx.x * 64 + tid] = lsum[tid];
        part[(size_t)blockIdx.x * 64 + 32 + tid] = lsq[tid];
    }
}

// ---------------- out = relu(bn5(h2)) @ lin_w + lin_b
__global__ __launch_bounds__(256)
void k_final(const float* __restrict__ h2, const float* __restrict__ sc,
             const float* __restrict__ sh, const float* __restrict__ lw,
             const float* __restrict__ lb, float* __restrict__ out, int N)
{
    int n = blockIdx.x * 256 + threadIdx.x;
    if (n >= N) return;
    const float* hr = h2 + (size_t)n * 32;
    float acc[26];
    #pragma unroll
    for (int o = 0; o < 26; ++o) acc[o] = lb[o];
    #pragma unroll
    for (int c4 = 0; c4 < 32; c4 += 4) {
        float4 hv = *(const float4*)(hr + c4);
        float xs[4] = { hv.x, hv.y, hv.z, hv.w };
        #pragma unroll
        for (int cc = 0; cc < 4; ++cc) {
            int c = c4 + cc;
            float x = fmaxf(xs[cc] * sc[c] + sh[c], 0.f);
            const float* wr = lw + c * 26;
            #pragma unroll
            for (int o = 0; o < 26; ++o) acc[o] += x * wr[o];
        }
    }
    float* orow = out + (size_t)n * 26;
    #pragma unroll
    for (int o = 0; o < 26; ++o) orow[o] = acc[o];
}

extern "C" void kernel_launch(void* const* d_in, const int* in_sizes, int n_in,
                              void* d_out, int out_size, void* d_ws, size_t ws_size,
                              hipStream_t stream)
{
    const float* feat_sem = (const float*)d_in[0];
    const float* feat_mos = (const float*)d_in[1];
    const float* fus_sp_w = (const float*)d_in[2];
    const float* fus_sp_b = (const float*)d_in[3];
    const float* fus_ch_w = (const float*)d_in[4];
    const float* fus_ch_b = (const float*)d_in[5];
    const float* conv_w   = (const float*)d_in[6];
    const float* conv_b   = (const float*)d_in[7];
    const float* r1c1_w   = (const float*)d_in[8];
    const float* r1g1     = (const float*)d_in[9];
    const float* r1b1     = (const float*)d_in[10];
    const float* r1c2_w   = (const float*)d_in[11];
    const float* r1g2     = (const float*)d_in[12];
    const float* r1b2     = (const float*)d_in[13];
    const float* ca1_w    = (const float*)d_in[14];
    const float* ca2_w    = (const float*)d_in[15];
    const float* r2c1_w   = (const float*)d_in[16];
    const float* r2g1     = (const float*)d_in[17];
    const float* r2b1     = (const float*)d_in[18];
    const float* r2c2_w   = (const float*)d_in[19];
    const float* r2g2     = (const float*)d_in[20];
    const float* r2b2     = (const float*)d_in[21];
    const float* out_g    = (const float*)d_in[22];
    const float* out_b    = (const float*)d_in[23];
    const float* lin_w    = (const float*)d_in[24];
    const float* lin_b    = (const float*)d_in[25];
    const int*   bids     = (const int*)d_in[26];
    const int*   nbr      = (const int*)d_in[27];
    int N = in_sizes[0] / 64;

    float* ws = (float*)d_ws;
    float* S1 = ws;                                   // 32N f32
    float* S2 = ws + (size_t)32 * N;                  // 32N f32
    float* S3 = ws + (size_t)64 * N;                  // 32N f32 (+pad)
    ushort* BB1 = (ushort*)(ws + (size_t)96 * N + 32);    // 32*(N+16) ushorts
    ushort* BB2 = BB1 + (size_t)32 * (N + 16);
    float* sbuf = S2;                                 // alias: dead before mconv1 writes S2
    ushort* FGB = (ushort*)S3;                        // alias: 64*(N+1) ushorts, dead before mconv2
    float* segpart = S1;                              // alias: dead before mconv0 writes S1
    float* st = ws + (size_t)128 * N + 1024;
    float* seg_fm = st;                   // 256
    float* cnt    = st + 256;             // 4
    float* vec    = st + 260;             // 256
    float* bnsc   = st + 516;             // 5*32
    float* bnsh   = st + 676;             // 5*32
    float* attbuf = st + 840;             // 128
    float* pcnt   = st + 1024;            // up to 2048
    float* ppbuf  = st + 4096;            // ((N+63)/64)*64
    float* partbuf= ppbuf + ((size_t)(N + 63) / 64) * 64 + 64;   // ((4N+255)/256)*256
    float* at2    = partbuf + ((size_t)4 * N + 255) / 256 * 256 + 256; // 64*256
    ushort* wpk0  = (ushort*)(at2 + 16384);  // 55296 + 4*27648 = 165888 ushorts
    ushort* wpk1 = wpk0 + 55296;
    ushort* wpk2 = wpk1 + 27648;
    ushort* wpk3 = wpk2 + 27648;
    ushort* wpk4 = wpk3 + 27648;
    int* nbrT = (int*)(wpk0 + 165888);       // 27N ints

    int nb  = (N + 255) / 256;     // 1 thr/voxel kernels
    int nb4 = (4 * N + 255) / 256; // 4 thr/voxel kernels
    int nb8 = (8 * N + 255) / 256; // 8 thr/voxel kernels
    int nw  = (N + 63) / 64;       // mconv: 64 voxels/block (4 waves x 16)
    const int NSEG = 512;
    float invN = 1.f / (float)N;

    k_wpack_all<<<81, 256, 0, stream>>>(conv_w, r1c1_w, r1c2_w, r2c1_w, r2c2_w, wpk0);
    k_nbrT<<<nw, 256, 0, stream>>>(nbr, nbrT, N);

    k_fuse_s<<<nb, 256, 0, stream>>>(feat_mos, fus_sp_w, fus_sp_b, bids, sbuf, pcnt, N);
    k_seg_part<<<NSEG, 256, 0, stream>>>(feat_sem, sbuf, bids, segpart, N);
    k_seg_red<<<1, 1024, 0, stream>>>(segpart, seg_fm, NSEG);
    k_vec<<<1, 256, 0, stream>>>(seg_fm, pcnt, nb, fus_ch_w, fus_ch_b, vec, cnt);
    k_gate_cvt<<<nb8, 256, 0, stream>>>(feat_sem, sbuf, vec, bids, FGB, N);

    k_mconv<64, false, true, true><<<nw, 256, 0, stream>>>(FGB, nbrT, wpk0, conv_b,
        S1, BB1, nullptr, N);

    k_mconv<32, true, false, false><<<nw, 256, 0, stream>>>(BB1, nbrT, wpk1, nullptr,
        S2, nullptr, ppbuf, N);
    k_statsr<<<1, 1024, 0, stream>>>(ppbuf, nw, r1g1, r1b1, bnsc + 0, bnsh + 0, invN);
    k_bnact<<<nb4, 256, 0, stream>>>(S2, bnsc + 0, bnsh + 0, BB2, N);

    k_mconv<32, true, false, false><<<nw, 256, 0, stream>>>(BB2, nbrT, wpk2, nullptr,
        S3, nullptr, ppbuf, N);
    k_statsr<<<1, 1024, 0, stream>>>(ppbuf, nw, r1g2, r1b2, bnsc + 32, bnsh + 32, invN);

    k_comb1<<<nb4, 256, 0, stream>>>(S3, bnsc + 32, bnsh + 32, bids, S1, partbuf, N);
    k_attred<<<64, 256, 0, stream>>>(partbuf, nb4, at2);
    k_att<<<1, 256, 0, stream>>>(at2, cnt, ca1_w, ca2_w, attbuf);
    k_scale_cvt<<<nb4, 256, 0, stream>>>(S1, attbuf, bids, S2, BB1, N);

    k_mconv<32, true, false, false><<<nw, 256, 0, stream>>>(BB1, nbrT, wpk3, nullptr,
        S3, nullptr, ppbuf, N);
    k_statsr<<<1, 1024, 0, stream>>>(ppbuf, nw, r2g1, r2b1, bnsc + 64, bnsh + 64, invN);
    k_bnact<<<nb4, 256, 0, stream>>>(S3, bnsc + 64, bnsh + 64, BB2, N);

    k_mconv<32, true, false, false><<<nw, 256, 0, stream>>>(BB2, nbrT, wpk4, nullptr,
        S1, nullptr, ppbuf, N);
    k_statsr<<<1, 1024, 0, stream>>>(ppbuf, nw, r2g2, r2b2, bnsc + 96, bnsh + 96, invN);

    k_comb2<<<nb4, 256, 0, stream>>>(S1, bnsc + 96, bnsh + 96, S2, ppbuf, N);
    k_statsr<<<1, 1024, 0, stream>>>(ppbuf, nb4, out_g, out_b, bnsc + 128, bnsh + 128, invN);

    k_final<<<nb, 256, 0, stream>>>(S2, bnsc + 128, bnsh + 128, lin_w, lin_b, (float*)d_out, N);
}

// Round 8
// 488.903 us; speedup vs baseline: 3.1435x; 1.0055x over previous
//
#include <hip/hip_runtime.h>
#include <math.h>

#define BMAX 4
typedef __attribute__((ext_vector_type(8))) short s16x8;
typedef __attribute__((ext_vector_type(4))) float f32x4;

__device__ __forceinline__ float sigmoidf_(float x) { return 1.f / (1.f + expf(-x)); }

// f32 -> bf16 RNE
__device__ __forceinline__ ushort f2b(float f) {
    uint u = __float_as_uint(f);
    u = u + 0x7FFFu + ((u >> 16) & 1u);
    return (ushort)(u >> 16);
}
__device__ __forceinline__ uint pk2(float a, float b) {
    return (uint)f2b(a) | ((uint)f2b(b) << 16);
}

// ---------------- transpose nbr [N][27] -> nbrT [27][N] (LDS-tiled, coalesced both sides)
__global__ __launch_bounds__(256)
void k_nbrT(const int* __restrict__ nbr, int* __restrict__ nbrT, int N)
{
    __shared__ int l[64 * 27];
    int tid = threadIdx.x;
    int n0 = blockIdx.x * 64;
    int nrows = min(64, N - n0);
    int tot = nrows * 27;
    for (int t = tid; t < tot; t += 256) l[t] = nbr[(size_t)n0 * 27 + t];
    __syncthreads();
    int lane = tid & 63;
    if (lane < nrows) {
        for (int k = tid >> 6; k < 27; k += 4)
            nbrT[(size_t)k * N + n0 + lane] = l[lane * 27 + k];
    }
}

// ---------------- fusion gate: s[n] = sigmoid(feat_mos[n].w+b); per-block batch counts
__global__ __launch_bounds__(256)
void k_fuse_s(const float* __restrict__ mos, const float* __restrict__ spw,
              const float* __restrict__ spb, const int* __restrict__ bids,
              float* __restrict__ s_out, float* __restrict__ pc, int N)
{
    __shared__ float lcnt[BMAX];
    int tid = threadIdx.x;
    if (tid < BMAX) lcnt[tid] = 0.f;
    __syncthreads();
    int n = blockIdx.x * 256 + tid;
    if (n < N) {
        const float* mr = mos + (size_t)n * 64;
        float dot = 0.f;
        #pragma unroll
        for (int c = 0; c < 64; c += 4) {
            float4 m4 = *(const float4*)(mr + c);
            float4 w4 = *(const float4*)(spw + c);
            dot += m4.x * w4.x + m4.y * w4.y + m4.z * w4.z + m4.w * w4.w;
        }
        float s = sigmoidf_(dot + spb[0]);
        s_out[n] = s;
        atomicAdd(&lcnt[bids[n]], 1.f);
    }
    __syncthreads();
    if (tid < BMAX) pc[(size_t)blockIdx.x * 4 + tid] = lcnt[tid];
}

// ---------------- stage 1: per-block partial seg-sums of fm = s[n]*feat_sem[n,c]
__global__ __launch_bounds__(256)
void k_seg_part(const float* __restrict__ fsem, const float* __restrict__ s_buf,
                const int* __restrict__ bids, float* __restrict__ part, int N)
{
    __shared__ float lseg[BMAX * 64];
    int tid = threadIdx.x;
    lseg[tid] = 0.f;
    __syncthreads();
    int c = tid & 63;
    int slot = blockIdx.x * 4 + (tid >> 6);
    int nslots = gridDim.x * 4;
    int chunk = (N + nslots - 1) / nslots;
    int n0 = slot * chunk;
    int n1 = min(N, n0 + chunk);
    float acc = 0.f; int curb = -1;
    int n = n0;
    for (; n + 4 <= n1; n += 4) {
        int b0 = bids[n], b3 = bids[n + 3];
        float s0 = s_buf[n], s1 = s_buf[n + 1], s2 = s_buf[n + 2], s3 = s_buf[n + 3];
        float f0 = fsem[(size_t)n * 64 + c];
        float f1 = fsem[(size_t)(n + 1) * 64 + c];
        float f2 = fsem[(size_t)(n + 2) * 64 + c];
        float f3 = fsem[(size_t)(n + 3) * 64 + c];
        if (b0 == b3) {
            if (b0 != curb) {
                if (curb >= 0) atomicAdd(&lseg[curb * 64 + c], acc);
                acc = 0.f; curb = b0;
            }
            acc += s0 * f0 + s1 * f1 + s2 * f2 + s3 * f3;
        } else {
            int bb[4] = { b0, bids[n + 1], bids[n + 2], b3 };
            float sv[4] = { s0, s1, s2, s3 };
            float fv[4] = { f0, f1, f2, f3 };
            #pragma unroll
            for (int q = 0; q < 4; ++q) {
                if (bb[q] != curb) {
                    if (curb >= 0) atomicAdd(&lseg[curb * 64 + c], acc);
                    acc = 0.f; curb = bb[q];
                }
                acc += sv[q] * fv[q];
            }
        }
    }
    for (; n < n1; ++n) {
        int b = bids[n];
        if (b != curb) {
            if (curb >= 0) atomicAdd(&lseg[curb * 64 + c], acc);
            acc = 0.f; curb = b;
        }
        acc += s_buf[n] * fsem[(size_t)n * 64 + c];
    }
    if (curb >= 0) atomicAdd(&lseg[curb * 64 + c], acc);
    __syncthreads();
    part[(size_t)blockIdx.x * 256 + tid] = lseg[tid];
}

// ---------------- stage 2: reduce partials -> seg[256]
__global__ __launch_bounds__(1024)
void k_seg_red(const float* __restrict__ part, float* __restrict__ seg, int nblk)
{
    __shared__ float l[1024];
    int tid = threadIdx.x;
    int col = tid & 255, grp = tid >> 8;
    float a = 0.f;
    #pragma unroll 8
    for (int j = grp; j < nblk; j += 4) a += part[(size_t)j * 256 + col];
    l[tid] = a;
    __syncthreads();
    if (tid < 256) seg[tid] = l[tid] + l[256 + tid] + l[512 + tid] + l[768 + tid];
}

// ---------------- vec = softmax(seg_mean @ fus_ch_w + b)*64; also reduces counts
__global__ void k_vec(const float* __restrict__ seg, const float* __restrict__ pc, int nbc,
                      const float* __restrict__ chw, const float* __restrict__ chb,
                      float* __restrict__ vec, float* __restrict__ cnt_out)
{
    __shared__ float lred[256];
    __shared__ float lcnt[4];
    int tid = threadIdx.x;
    float a = 0.f;
    for (int j = tid >> 2; j < nbc; j += 64) a += pc[(size_t)j * 4 + (tid & 3)];
    lred[tid] = a;
    __syncthreads();
    if (tid < 4) {
        float s = 0.f;
        #pragma unroll 8
        for (int j = 0; j < 64; ++j) s += lred[j * 4 + tid];
        lcnt[tid] = s;
        cnt_out[tid] = s;
    }
    __syncthreads();
    int b = tid >> 6;
    int c = tid & 63;
    float mean = seg[b * 64 + c] / lcnt[b];
    float v = chb[c];
    #pragma unroll 1
    for (int i = 0; i < 64; ++i) {
        float mi = __shfl(mean, i, 64);
        v += mi * chw[i * 64 + c];
    }
    float m = v;
    #pragma unroll
    for (int off = 32; off; off >>= 1) m = fmaxf(m, __shfl_xor(m, off, 64));
    float e = expf(v - m);
    float ssum = e;
    #pragma unroll
    for (int off = 32; off; off >>= 1) ssum += __shfl_xor(ssum, off, 64);
    vec[b * 64 + c] = e / ssum * 64.f;
}

// ---------------- gated input -> bf16 (8 thr/voxel); writes zero row N
__global__ __launch_bounds__(256)
void k_gate_cvt(const float* __restrict__ fs, const float* __restrict__ s_buf,
                const float* __restrict__ vec, const int* __restrict__ bids,
                ushort* __restrict__ out, int N)
{
    int gid = blockIdx.x * 256 + threadIdx.x;
    if (gid < 64) out[(size_t)N * 64 + gid] = 0;
    int n = gid >> 3;
    if (n >= N) return;
    int c0 = (gid & 7) * 8;
    float s = s_buf[n];
    const float* vr = vec + bids[n] * 64 + c0;
    const float* fr = fs + (size_t)n * 64 + c0;
    float4 f0 = *(const float4*)fr, f1 = *(const float4*)(fr + 4);
    float4 v0 = *(const float4*)vr, v1 = *(const float4*)(vr + 4);
    float g0 = f0.x * (1.f + s * v0.x), g1 = f0.y * (1.f + s * v0.y);
    float g2 = f0.z * (1.f + s * v0.z), g3 = f0.w * (1.f + s * v0.w);
    float g4 = f1.x * (1.f + s * v1.x), g5 = f1.y * (1.f + s * v1.y);
    float g6 = f1.z * (1.f + s * v1.z), g7 = f1.w * (1.f + s * v1.w);
    uint4 o; o.x = pk2(g0, g1); o.y = pk2(g2, g3); o.z = pk2(g4, g5); o.w = pk2(g6, g7);
    *(uint4*)(out + (size_t)n * 64 + c0) = o;
}

// ---------------- pack one weight element into MFMA B-fragment layout
__device__ __forceinline__ void wpack_one(const float* __restrict__ W, int CIN,
                                          int tt, ushort* __restrict__ dst)
{
    int nkc = CIN >> 5;
    int lane = tt & 63;
    int nt = (tt >> 6) & 1;
    int kc = (tt >> 7) % nkc;
    int k = tt / (nkc * 128);
    int kk = kc * 32 + (lane >> 4) * 8;
    int col = nt * 16 + (lane & 15);
    const float* src = W + ((size_t)k * CIN + kk) * 32 + col;
    float v[8];
    #pragma unroll
    for (int e = 0; e < 8; ++e) v[e] = src[e * 32];
    uint4 o; o.x = pk2(v[0], v[1]); o.y = pk2(v[2], v[3]);
    o.z = pk2(v[4], v[5]); o.w = pk2(v[6], v[7]);
    *(uint4*)(dst + (size_t)tt * 8) = o;
}

__global__ __launch_bounds__(256)
void k_wpack_all(const float* __restrict__ W0, const float* __restrict__ W1,
                 const float* __restrict__ W2, const float* __restrict__ W3,
                 const float* __restrict__ W4, ushort* __restrict__ P)
{
    int t = blockIdx.x * 256 + threadIdx.x;
    if (t < 6912) {
        wpack_one(W0, 64, t, P);
    } else {
        int r = t - 6912;
        int s = r / 3456;
        int tt = r % 3456;
        if (s >= 4) return;
        const float* W = (s == 0) ? W1 : (s == 1) ? W2 : (s == 2) ? W3 : W4;
        wpack_one(W, 32, tt, P + 55296 + s * 27648);
    }
}

// ---------------- MFMA gather-conv: wave = 16 voxels (1 M-tile), 32 out-ch (2 N-tiles)
// branchless zero-page gathers; SW-pipelined in groups of 9 in-flight gather loads
template<int CIN, bool STATS, bool BIAS, bool WB16>
__global__ __launch_bounds__(256)
void k_mconv(const ushort* __restrict__ inb, const int* __restrict__ nbrT,
             const ushort* __restrict__ wpk, const float* __restrict__ bias,
             float* __restrict__ outf, ushort* __restrict__ outb,
             float* __restrict__ pp, int N)
{
    constexpr int NKC = CIN / 32;
    constexpr int T = 27 * NKC;     // flattened (tap, kc) steps
    constexpr int G = 9;            // gather prefetch group
    __shared__ float lsum[32];
    __shared__ float lsq[32];
    int tid = threadIdx.x;
    if (WB16 && blockIdx.x == 0 && tid < 32) outb[(size_t)N * 32 + tid] = 0;
    if (STATS) {
        if (tid < 32) { lsum[tid] = 0.f; lsq[tid] = 0.f; }
        __syncthreads();
    }
    int lane = tid & 63;
    int gw = (blockIdx.x * 256 + tid) >> 6;
    int vbase = gw * 16;
    float ps0 = 0.f, pq0 = 0.f, ps1 = 0.f, pq1 = 0.f;
    if (vbase < N) {
        int row = lane & 15;
        int koff = (lane >> 4) * 8;
        int vr = vbase + row; if (vr >= N) vr = N - 1;
        f32x4 acc0 = {0.f,0.f,0.f,0.f}, acc1 = {0.f,0.f,0.f,0.f};
        int j[27];
        #pragma unroll
        for (int k = 0; k < 27; ++k) j[k] = nbrT[(size_t)k * N + vr];
        #pragma unroll
        for (int g = 0; g < T; g += G) {
            s16x8 a[G];
            #pragma unroll
            for (int q = 0; q < G; ++q) {
                int t = g + q;
                int k = t / NKC, kc = t % NKC;
                int jj = (j[k] < 0) ? N : j[k];
                a[q] = *(const s16x8*)(inb + (size_t)jj * CIN + kc * 32 + koff);
            }
            #pragma unroll
            for (int q = 0; q < G; ++q) {
                const ushort* wb = wpk + (size_t)(g + q) * 1024 + lane * 8;
                s16x8 b0 = *(const s16x8*)(wb);
                s16x8 b1 = *(const s16x8*)(wb + 512);
                acc0 = __builtin_amdgcn_mfma_f32_16x16x32_bf16(a[q], b0, acc0, 0, 0, 0);
                acc1 = __builtin_amdgcn_mfma_f32_16x16x32_bf16(a[q], b1, acc1, 0, 0, 0);
            }
        }
        int ccol = lane & 15;
        int crow = (lane >> 4) * 4;
        float b0v = BIAS ? bias[ccol] : 0.f;
        float b1v = BIAS ? bias[16 + ccol] : 0.f;
        #pragma unroll
        for (int i = 0; i < 4; ++i) {
            int v = vbase + crow + i;
            if (v < N) {
                float x0 = acc0[i] + b0v;
                float x1 = acc1[i] + b1v;
                outf[(size_t)v * 32 + ccol] = x0;
                outf[(size_t)v * 32 + 16 + ccol] = x1;
                if (WB16) {
                    outb[(size_t)v * 32 + ccol] = f2b(x0);
                    outb[(size_t)v * 32 + 16 + ccol] = f2b(x1);
                }
                if (STATS) { ps0 += x0; pq0 += x0 * x0; ps1 += x1; pq1 += x1 * x1; }
            }
        }
    }
    if (STATS) {
        ps0 += __shfl_xor(ps0, 16, 64); ps0 += __shfl_xor(ps0, 32, 64);
        pq0 += __shfl_xor(pq0, 16, 64); pq0 += __shfl_xor(pq0, 32, 64);
        ps1 += __shfl_xor(ps1, 16, 64); ps1 += __shfl_xor(ps1, 32, 64);
        pq1 += __shfl_xor(pq1, 16, 64); pq1 += __shfl_xor(pq1, 32, 64);
        if (lane < 16) {
            atomicAdd(&lsum[lane], ps0);
            atomicAdd(&lsq[lane], pq0);
            atomicAdd(&lsum[16 + lane], ps1);
            atomicAdd(&lsq[16 + lane], pq1);
        }
        __syncthreads();
        if (tid < 32) {
            pp[(size_t)blockIdx.x * 64 + tid] = lsum[tid];
            pp[(size_t)blockIdx.x * 64 + 32 + tid] = lsq[tid];
        }
    }
}

// ---------------- reduce stats partials [nblk][64] + compute BN scale/shift
__global__ __launch_bounds__(1024)
void k_statsr(const float* __restrict__ part, int nblk,
              const float* __restrict__ g, const float* __restrict__ bb,
              float* __restrict__ sc, float* __restrict__ sh, float invN)
{
    __shared__ float l[1024];
    int tid = threadIdx.x;
    int col = tid & 63, grp = tid >> 6;
    float a = 0.f;
    #pragma unroll 8
    for (int j = grp; j < nblk; j += 16) a += part[(size_t)j * 64 + col];
    l[tid] = a;
    __syncthreads();
    if (tid < 64) {
        float s = 0.f;
        #pragma unroll
        for (int gq = 0; gq < 16; ++gq) s += l[gq * 64 + tid];
        l[tid] = s;
    }
    __syncthreads();
    if (tid < 32) {
        float m = l[tid] * invN;
        float v = l[32 + tid] * invN - m * m;
        float s = g[tid] * rsqrtf(v + 1e-4f);
        sc[tid] = s;
        sh[tid] = bb[tid] - m * s;
    }
}

// ---------------- a_b = bf16(relu(t*sc+sh)) (4 thr/voxel); writes zero row N
__global__ __launch_bounds__(256)
void k_bnact(const float* __restrict__ t, const float* __restrict__ sc,
             const float* __restrict__ sh, ushort* __restrict__ out, int N)
{
    int gid = blockIdx.x * 256 + threadIdx.x;
    if (gid < 32) out[(size_t)N * 32 + gid] = 0;
    int n = gid >> 2;
    if (n >= N) return;
    int c0 = (gid & 3) * 8;
    const float* tr = t + (size_t)n * 32 + c0;
    float4 t0 = *(const float4*)tr, t1 = *(const float4*)(tr + 4);
    float g0 = fmaxf(t0.x * sc[c0+0] + sh[c0+0], 0.f);
    float g1 = fmaxf(t0.y * sc[c0+1] + sh[c0+1], 0.f);
    float g2 = fmaxf(t0.z * sc[c0+2] + sh[c0+2], 0.f);
    float g3 = fmaxf(t0.w * sc[c0+3] + sh[c0+3], 0.f);
    float g4 = fmaxf(t1.x * sc[c0+4] + sh[c0+4], 0.f);
    float g5 = fmaxf(t1.y * sc[c0+5] + sh[c0+5], 0.f);
    float g6 = fmaxf(t1.z * sc[c0+6] + sh[c0+6], 0.f);
    float g7 = fmaxf(t1.w * sc[c0+7] + sh[c0+7], 0.f);
    uint4 o; o.x = pk2(g0, g1); o.y = pk2(g2, g3); o.z = pk2(g4, g5); o.w = pk2(g6, g7);
    *(uint4*)(out + (size_t)n * 32 + c0) = o;
}

// ---------------- h1 = relu(bn(t)+h) IN-PLACE on hr; per-block (b,c) sum/max partials
__global__ __launch_bounds__(256)
void k_comb1(const float* __restrict__ t, const float* __restrict__ sc,
             const float* __restrict__ sh, const int* __restrict__ bids,
             float* hr, float* __restrict__ part, int N)
{
    __shared__ float lsum[BMAX * 32];
    __shared__ int   lmax[BMAX * 32];
    int tid = threadIdx.x;
    if (tid < BMAX * 32) { lsum[tid] = 0.f; lmax[tid] = 0; }
    __syncthreads();
    int gid = blockIdx.x * 256 + tid;
    int n = gid >> 2;
    int c0 = (gid & 3) * 8;
    if (n < N) {
        int b = bids[n];
        const float* tr = t + (size_t)n * 32 + c0;
        float* rr = hr + (size_t)n * 32 + c0;
        float4 t0 = *(const float4*)tr, t1 = *(const float4*)(tr + 4);
        float4 r0 = *(const float4*)rr, r1 = *(const float4*)(rr + 4);
        float v[8];
        v[0] = fmaxf(t0.x * sc[c0+0] + sh[c0+0] + r0.x, 0.f);
        v[1] = fmaxf(t0.y * sc[c0+1] + sh[c0+1] + r0.y, 0.f);
        v[2] = fmaxf(t0.z * sc[c0+2] + sh[c0+2] + r0.z, 0.f);
        v[3] = fmaxf(t0.w * sc[c0+3] + sh[c0+3] + r0.w, 0.f);
        v[4] = fmaxf(t1.x * sc[c0+4] + sh[c0+4] + r1.x, 0.f);
        v[5] = fmaxf(t1.y * sc[c0+5] + sh[c0+5] + r1.y, 0.f);
        v[6] = fmaxf(t1.z * sc[c0+6] + sh[c0+6] + r1.z, 0.f);
        v[7] = fmaxf(t1.w * sc[c0+7] + sh[c0+7] + r1.w, 0.f);
        float4 o0 = { v[0], v[1], v[2], v[3] };
        float4 o1 = { v[4], v[5], v[6], v[7] };
        *(float4*)rr = o0;
        *(float4*)(rr + 4) = o1;
        int base = b * 32 + c0;
        #pragma unroll
        for (int i = 0; i < 8; ++i) {
            atomicAdd(&lsum[base + i], v[i]);
            atomicMax(&lmax[base + i], __float_as_int(v[i]));
        }
    }
    __syncthreads();
    if (tid < 128) part[(size_t)blockIdx.x * 256 + tid] = lsum[tid];
    else           part[(size_t)blockIdx.x * 256 + tid] = __int_as_float(lmax[tid - 128]);
}

// ---------------- stage 1 reduce of comb1 partials: [nblk][256] -> [64][256]
__global__ __launch_bounds__(256)
void k_attred(const float* __restrict__ part, int nblk, float* __restrict__ out)
{
    int tid = threadIdx.x;
    int blk = blockIdx.x;
    if (tid < 128) {
        float a = 0.f;
        #pragma unroll 4
        for (int j = blk; j < nblk; j += 64) a += part[(size_t)j * 256 + tid];
        out[(size_t)blk * 256 + tid] = a;
    } else {
        float m = 0.f;
        #pragma unroll 4
        for (int j = blk; j < nblk; j += 64) m = fmaxf(m, part[(size_t)j * 256 + tid]);
        out[(size_t)blk * 256 + tid] = m;
    }
}

// ---------------- channel attention
__global__ void k_att(const float* __restrict__ part2, const float* __restrict__ cnt,
                      const float* __restrict__ ca1, const float* __restrict__ ca2,
                      float* __restrict__ att)
{
    __shared__ float seg[256];
    int tid = threadIdx.x;
    if (tid < 128) {
        float a = 0.f;
        #pragma unroll 8
        for (int j = 0; j < 64; ++j) a += part2[j * 256 + tid];
        seg[tid] = a;
    } else {
        float m = 0.f;
        #pragma unroll 8
        for (int j = 0; j < 64; ++j) m = fmaxf(m, part2[j * 256 + tid]);
        seg[tid] = m;
    }
    __syncthreads();
    int b = tid >> 6;
    int lane = tid & 63;
    bool actc = lane < 32;
    int c = lane & 31;
    float avg = actc ? seg[b * 32 + c] / cnt[b] : 0.f;
    float mx  = actc ? seg[128 + b * 32 + c] : 0.f;
    float h[8];
    #pragma unroll
    for (int i = 0; i < 4; ++i) {
        float w = actc ? ca1[c * 4 + i] : 0.f;
        h[i] = avg * w;
        h[i + 4] = mx * w;
    }
    #pragma unroll
    for (int off = 32; off; off >>= 1) {
        #pragma unroll
        for (int i = 0; i < 8; ++i) h[i] += __shfl_xor(h[i], off, 64);
    }
    if (actc) {
        float o = 0.f;
        #pragma unroll
        for (int i = 0; i < 4; ++i)
            o += (fmaxf(h[i], 0.f) + fmaxf(h[i + 4], 0.f)) * ca2[i * 32 + c];
        att[b * 32 + c] = sigmoidf_(o);
    }
}

// ---------------- hatt = h1*att[b] (4 thr/voxel); f32 + bf16 mirror; zero row N of bf16
__global__ __launch_bounds__(256)
void k_scale_cvt(const float* __restrict__ h1, const float* __restrict__ att,
                 const int* __restrict__ bids, float* __restrict__ hatt,
                 ushort* __restrict__ hattb, int N)
{
    int gid = blockIdx.x * 256 + threadIdx.x;
    if (gid < 32) hattb[(size_t)N * 32 + gid] = 0;
    int n = gid >> 2;
    if (n >= N) return;
    int c0 = (gid & 3) * 8;
    const float* hrp = h1 + (size_t)n * 32 + c0;
    const float* ar = att + bids[n] * 32 + c0;
    float4 h0 = *(const float4*)hrp, h1v = *(const float4*)(hrp + 4);
    float4 a0 = *(const float4*)ar, a1 = *(const float4*)(ar + 4);
    float g0 = h0.x * a0.x, g1 = h0.y * a0.y, g2 = h0.z * a0.z, g3 = h0.w * a0.w;
    float g4 = h1v.x * a1.x, g5 = h1v.y * a1.y, g6 = h1v.z * a1.z, g7 = h1v.w * a1.w;
    float4 w0 = { g0, g1, g2, g3 };
    float4 w1 = { g4, g5, g6, g7 };
    *(float4*)(hatt + (size_t)n * 32 + c0) = w0;
    *(float4*)(hatt + (size_t)n * 32 + c0 + 4) = w1;
    uint4 o; o.x = pk2(g0, g1); o.y = pk2(g2, g3); o.z = pk2(g4, g5); o.w = pk2(g6, g7);
    *(uint4*)(hattb + (size_t)n * 32 + c0) = o;
}

// ---------------- h2 = relu(bn(t)+hres) IN-PLACE on hr; partial sums for final BN
__global__ __launch_bounds__(256)
void k_comb2(const float* __restrict__ t, const float* __restrict__ sc,
             const float* __restrict__ sh, float* hr, float* __restrict__ part, int N)
{
    __shared__ float lsum[32];
    __shared__ float lsq[32];
    int tid = threadIdx.x;
    if (tid < 32) { lsum[tid] = 0.f; lsq[tid] = 0.f; }
    __syncthreads();
    int gid = blockIdx.x * 256 + tid;
    int n = gid >> 2;
    int c0 = (gid & 3) * 8;
    if (n < N) {
        const float* tr = t + (size_t)n * 32 + c0;
        float* rr = hr + (size_t)n * 32 + c0;
        float4 t0 = *(const float4*)tr, t1 = *(const float4*)(tr + 4);
        float4 h0 = *(const float4*)rr, h1 = *(const float4*)(rr + 4);
        float v[8];
        v[0] = fmaxf(t0.x * sc[c0+0] + sh[c0+0] + h0.x, 0.f);
        v[1] = fmaxf(t0.y * sc[c0+1] + sh[c0+1] + h0.y, 0.f);
        v[2] = fmaxf(t0.z * sc[c0+2] + sh[c0+2] + h0.z, 0.f);
        v[3] = fmaxf(t0.w * sc[c0+3] + sh[c0+3] + h0.w, 0.f);
        v[4] = fmaxf(t1.x * sc[c0+4] + sh[c0+4] + h1.x, 0.f);
        v[5] = fmaxf(t1.y * sc[c0+5] + sh[c0+5] + h1.y, 0.f);
        v[6] = fmaxf(t1.z * sc[c0+6] + sh[c0+6] + h1.z, 0.f);
        v[7] = fmaxf(t1.w * sc[c0+7] + sh[c0+7] + h1.w, 0.f);
        float4 o0 = { v[0], v[1], v[2], v[3] };
        float4 o1 = { v[4], v[5], v[6], v[7] };
        *(float4*)rr = o0;
        *(float4*)(rr + 4) = o1;
        #pragma unroll
        for (int i = 0; i < 8; ++i) {
            atomicAdd(&lsum[c0 + i], v[i]);
            atomicAdd(&lsq[c0 + i], v[i] * v[i]);
        }
    }
    __syncthreads();
    if (tid < 32) {
        part[(size_t)blockIdx.x * 64 + tid] = lsum[tid];
        part[(size_t)blockIdx.x * 64 + 32 + tid] = lsq[tid];
    }
}

// ---------------- out = relu(bn5(h2)) @ lin_w + lin_b
__global__ __launch_bounds__(256)
void k_final(const float* __restrict__ h2, const float* __restrict__ sc,
             const float* __restrict__ sh, const float* __restrict__ lw,
             const float* __restrict__ lb, float* __restrict__ out, int N)
{
    int n = blockIdx.x * 256 + threadIdx.x;
    if (n >= N) return;
    const float* hr = h2 + (size_t)n * 32;
    float acc[26];
    #pragma unroll
    for (int o = 0; o < 26; ++o) acc[o] = lb[o];
    #pragma unroll
    for (int c4 = 0; c4 < 32; c4 += 4) {
        float4 hv = *(const float4*)(hr + c4);
        float xs[4] = { hv.x, hv.y, hv.z, hv.w };
        #pragma unroll
        for (int cc = 0; cc < 4; ++cc) {
            int c = c4 + cc;
            float x = fmaxf(xs[cc] * sc[c] + sh[c], 0.f);
            const float* wr = lw + c * 26;
            #pragma unroll
            for (int o = 0; o < 26; ++o) acc[o] += x * wr[o];
        }
    }
    float* orow = out + (size_t)n * 26;
    #pragma unroll
    for (int o = 0; o < 26; ++o) orow[o] = acc[o];
}

extern "C" void kernel_launch(void* const* d_in, const int* in_sizes, int n_in,
                              void* d_out, int out_size, void* d_ws, size_t ws_size,
                              hipStream_t stream)
{
    const float* feat_sem = (const float*)d_in[0];
    const float* feat_mos = (const float*)d_in[1];
    const float* fus_sp_w = (const float*)d_in[2];
    const float* fus_sp_b = (const float*)d_in[3];
    const float* fus_ch_w = (const float*)d_in[4];
    const float* fus_ch_b = (const float*)d_in[5];
    const float* conv_w   = (const float*)d_in[6];
    const float* conv_b   = (const float*)d_in[7];
    const float* r1c1_w   = (const float*)d_in[8];
    const float* r1g1     = (const float*)d_in[9];
    const float* r1b1     = (const float*)d_in[10];
    const float* r1c2_w   = (const float*)d_in[11];
    const float* r1g2     = (const float*)d_in[12];
    const float* r1b2     = (const float*)d_in[13];
    const float* ca1_w    = (const float*)d_in[14];
    const float* ca2_w    = (const float*)d_in[15];
    const float* r2c1_w   = (const float*)d_in[16];
    const float* r2g1     = (const float*)d_in[17];
    const float* r2b1     = (const float*)d_in[18];
    const float* r2c2_w   = (const float*)d_in[19];
    const float* r2g2     = (const float*)d_in[20];
    const float* r2b2     = (const float*)d_in[21];
    const float* out_g    = (const float*)d_in[22];
    const float* out_b    = (const float*)d_in[23];
    const float* lin_w    = (const float*)d_in[24];
    const float* lin_b    = (const float*)d_in[25];
    const int*   bids     = (const int*)d_in[26];
    const int*   nbr      = (const int*)d_in[27];
    int N = in_sizes[0] / 64;

    float* ws = (float*)d_ws;
    float* S1 = ws;                                   // 32N f32
    float* S2 = ws + (size_t)32 * N;                  // 32N f32
    float* S3 = ws + (size_t)64 * N;                  // 32N f32 (+pad)
    ushort* BB1 = (ushort*)(ws + (size_t)96 * N + 32);    // 32*(N+16) ushorts
    ushort* BB2 = BB1 + (size_t)32 * (N + 16);
    float* sbuf = S2;                                 // alias: dead before mconv1 writes S2
    ushort* FGB = (ushort*)S3;                        // alias: 64*(N+1) ushorts, dead before mconv2
    float* segpart = S1;                              // alias: dead before mconv0 writes S1
    float* st = ws + (size_t)128 * N + 1024;
    float* seg_fm = st;                   // 256
    float* cnt    = st + 256;             // 4
    float* vec    = st + 260;             // 256
    float* bnsc   = st + 516;             // 5*32
    float* bnsh   = st + 676;             // 5*32
    float* attbuf = st + 840;             // 128
    float* pcnt   = st + 1024;            // up to 2048
    float* ppbuf  = st + 4096;            // ((N+63)/64)*64
    float* partbuf= ppbuf + ((size_t)(N + 63) / 64) * 64 + 64;   // ((4N+255)/256)*256
    float* at2    = partbuf + ((size_t)4 * N + 255) / 256 * 256 + 256; // 64*256
    ushort* wpk0  = (ushort*)(at2 + 16384);  // 55296 + 4*27648 = 165888 ushorts
    ushort* wpk1 = wpk0 + 55296;
    ushort* wpk2 = wpk1 + 27648;
    ushort* wpk3 = wpk2 + 27648;
    ushort* wpk4 = wpk3 + 27648;
    int* nbrT = (int*)(wpk0 + 165888);       // 27N ints

    int nb  = (N + 255) / 256;     // 1 thr/voxel kernels
    int nb4 = (4 * N + 255) / 256; // 4 thr/voxel kernels
    int nb8 = (8 * N + 255) / 256; // 8 thr/voxel kernels
    int nw  = (N + 63) / 64;       // mconv: 64 voxels/block (4 waves x 16)
    const int NSEG = 512;
    float invN = 1.f / (float)N;

    k_wpack_all<<<81, 256, 0, stream>>>(conv_w, r1c1_w, r1c2_w, r2c1_w, r2c2_w, wpk0);
    k_nbrT<<<nw, 256, 0, stream>>>(nbr, nbrT, N);

    k_fuse_s<<<nb, 256, 0, stream>>>(feat_mos, fus_sp_w, fus_sp_b, bids, sbuf, pcnt, N);
    k_seg_part<<<NSEG, 256, 0, stream>>>(feat_sem, sbuf, bids, segpart, N);
    k_seg_red<<<1, 1024, 0, stream>>>(segpart, seg_fm, NSEG);
    k_vec<<<1, 256, 0, stream>>>(seg_fm, pcnt, nb, fus_ch_w, fus_ch_b, vec, cnt);
    k_gate_cvt<<<nb8, 256, 0, stream>>>(feat_sem, sbuf, vec, bids, FGB, N);

    k_mconv<64, false, true, true><<<nw, 256, 0, stream>>>(FGB, nbrT, wpk0, conv_b,
        S1, BB1, nullptr, N);

    k_mconv<32, true, false, false><<<nw, 256, 0, stream>>>(BB1, nbrT, wpk1, nullptr,
        S2, nullptr, ppbuf, N);
    k_statsr<<<1, 1024, 0, stream>>>(ppbuf, nw, r1g1, r1b1, bnsc + 0, bnsh + 0, invN);
    k_bnact<<<nb4, 256, 0, stream>>>(S2, bnsc + 0, bnsh + 0, BB2, N);

    k_mconv<32, true, false, false><<<nw, 256, 0, stream>>>(BB2, nbrT, wpk2, nullptr,
        S3, nullptr, ppbuf, N);
    k_statsr<<<1, 1024, 0, stream>>>(ppbuf, nw, r1g2, r1b2, bnsc + 32, bnsh + 32, invN);

    k_comb1<<<nb4, 256, 0, stream>>>(S3, bnsc + 32, bnsh + 32, bids, S1, partbuf, N);
    k_attred<<<64, 256, 0, stream>>>(partbuf, nb4, at2);
    k_att<<<1, 256, 0, stream>>>(at2, cnt, ca1_w, ca2_w, attbuf);
    k_scale_cvt<<<nb4, 256, 0, stream>>>(S1, attbuf, bids, S2, BB1, N);

    k_mconv<32, true, false, false><<<nw, 256, 0, stream>>>(BB1, nbrT, wpk3, nullptr,
        S3, nullptr, ppbuf, N);
    k_statsr<<<1, 1024, 0, stream>>>(ppbuf, nw, r2g1, r2b1, bnsc + 64, bnsh + 64, invN);
    k_bnact<<<nb4, 256, 0, stream>>>(S3, bnsc + 64, bnsh + 64, BB2, N);

    k_mconv<32, true, false, false><<<nw, 256, 0, stream>>>(BB2, nbrT, wpk4, nullptr,
        S1, nullptr, ppbuf, N);
    k_statsr<<<1, 1024, 0, stream>>>(ppbuf, nw, r2g2, r2b2, bnsc + 96, bnsh + 96, invN);

    k_comb2<<<nb4, 256, 0, stream>>>(S1, bnsc + 96, bnsh + 96, S2, ppbuf, N);
    k_statsr<<<1, 1024, 0, stream>>>(ppbuf, nb4, out_g, out_b, bnsc + 128, bnsh + 128, invN);

    k_final<<<nb, 256, 0, stream>>>(S2, bnsc + 128, bnsh + 128, lin_w, lin_b, (float*)d_out, N);
}